// Round 1
// baseline (3324.065 us; speedup 1.0000x reference)
//
#include <hip/hip_runtime.h>
#include <math.h>

#define BB 8
#define NN 2048
#define KK 20
#define XCCH 512
#define NSLOT 64
#define LEPS 1e-5f

__device__ __forceinline__ float lrelu(float x){ return x >= 0.f ? x : 0.2f*x; }

// ---------- transpose x (B,3,N) -> xt0 (B*N,4) (pad 0) ----------
__global__ __launch_bounds__(256) void k_transpose(const float* __restrict__ x, float* __restrict__ xt){
  int i = blockIdx.x*256 + threadIdx.x;
  if (i >= BB*NN) return;
  int b = i >> 11, n = i & (NN-1);
  float4 v;
  v.x = x[(b*3+0)*NN + n];
  v.y = x[(b*3+1)*NN + n];
  v.z = x[(b*3+2)*NN + n];
  v.w = 0.f;
  reinterpret_cast<float4*>(xt)[i] = v;
}

// ---------- squared norms ----------
__global__ __launch_bounds__(256) void k_sq(const float* __restrict__ P, int stride, int Ci, float* __restrict__ sq){
  int i = blockIdx.x*256 + threadIdx.x;
  if (i >= BB*NN) return;
  const float* p = P + (size_t)i*stride;
  float s = 0.f;
  for (int c = 0; c < Ci; ++c){ float v = p[c]; s += v*v; }
  sq[i] = s;
}

// ---------- pairwise score pd = 2*dot - sq_n - sq_m (top-k of this = knn) ----------
__global__ __launch_bounds__(256) void k_dist(const float* __restrict__ P, int stride, int Ci,
                                              const float* __restrict__ sq, float* __restrict__ pd){
  __shared__ float At[128*17];
  __shared__ float Bt[128*17];
  int b = blockIdx.z;
  int n0 = blockIdx.y*128, m0 = blockIdx.x*128;
  int t = threadIdx.x;
  int ty = t >> 4, tx = t & 15;
  float acc[8][8];
  #pragma unroll
  for (int i=0;i<8;i++)
    #pragma unroll
    for (int j=0;j<8;j++) acc[i][j]=0.f;
  const float* Pb = P + (size_t)b*NN*stride;
  for (int c0 = 0; c0 < Ci; c0 += 16){
    #pragma unroll
    for (int q = 0; q < 8; ++q){
      int e = t + 256*q;
      int r = e >> 4, cc = e & 15;
      int c = c0 + cc;
      bool ok = (c < Ci);
      At[r*17+cc] = ok ? Pb[(size_t)(n0+r)*stride + c] : 0.f;
      Bt[r*17+cc] = ok ? Pb[(size_t)(m0+r)*stride + c] : 0.f;
    }
    __syncthreads();
    #pragma unroll
    for (int j = 0; j < 16; ++j){
      float a[8], bv[8];
      #pragma unroll
      for (int i=0;i<8;i++) a[i]  = At[(ty*8+i)*17 + j];
      #pragma unroll
      for (int i=0;i<8;i++) bv[i] = Bt[(tx*8+i)*17 + j];
      #pragma unroll
      for (int i=0;i<8;i++)
        #pragma unroll
        for (int jj=0;jj<8;jj++) acc[i][jj] += a[i]*bv[jj];
    }
    __syncthreads();
  }
  float sqn[8], sqm[8];
  #pragma unroll
  for (int i=0;i<8;i++) sqn[i] = sq[b*NN + n0 + ty*8 + i];
  #pragma unroll
  for (int i=0;i<8;i++) sqm[i] = sq[b*NN + m0 + tx*8 + i];
  #pragma unroll
  for (int i=0;i<8;i++){
    size_t base = ((size_t)b*NN + n0+ty*8+i)*NN + m0 + tx*8;
    float4 v0, v1;
    v0.x = 2.f*acc[i][0] - sqn[i] - sqm[0];
    v0.y = 2.f*acc[i][1] - sqn[i] - sqm[1];
    v0.z = 2.f*acc[i][2] - sqn[i] - sqm[2];
    v0.w = 2.f*acc[i][3] - sqn[i] - sqm[3];
    v1.x = 2.f*acc[i][4] - sqn[i] - sqm[4];
    v1.y = 2.f*acc[i][5] - sqn[i] - sqm[5];
    v1.z = 2.f*acc[i][6] - sqn[i] - sqm[6];
    v1.w = 2.f*acc[i][7] - sqn[i] - sqm[7];
    reinterpret_cast<float4*>(pd + base)[0] = v0;
    reinterpret_cast<float4*>(pd + base)[1] = v1;
  }
}

// ---------- top-20 per row (largest pd, ties -> lowest index, matches lax.top_k set) ----------
__global__ __launch_bounds__(256) void k_topk(const float* __restrict__ pd, int* __restrict__ idxo){
  __shared__ float wvs[4];
  __shared__ int wms[4];
  __shared__ int gb;
  int bid = blockIdx.x;
  int t = threadIdx.x;
  const float* row = pd + (size_t)bid*NN;
  float r[8];
  #pragma unroll
  for (int j=0;j<8;j++) r[j] = row[t + 256*j];
  int* o = idxo + bid*KK;
  for (int it=0; it<KK; ++it){
    float bv = r[0]; int bm = t;
    #pragma unroll
    for (int j=1;j<8;j++){
      if (r[j] > bv){ bv = r[j]; bm = t + 256*j; }
    }
    #pragma unroll
    for (int off=32; off>0; off>>=1){
      float ov = __shfl_down(bv, off);
      int om = __shfl_down(bm, off);
      if (ov > bv || (ov == bv && om < bm)){ bv = ov; bm = om; }
    }
    if ((t & 63) == 0){ wvs[t>>6] = bv; wms[t>>6] = bm; }
    __syncthreads();
    if (t == 0){
      float fv = wvs[0]; int fm = wms[0];
      for (int w2=1; w2<4; ++w2){
        if (wvs[w2] > fv || (wvs[w2] == fv && wms[w2] < fm)){ fv = wvs[w2]; fm = wms[w2]; }
      }
      o[it] = fm;
      gb = fm;
    }
    __syncthreads();
    int bm2 = gb;
    #pragma unroll
    for (int j=0;j<8;j++){
      if (bm2 == t + 256*j) r[j] = -3.4e38f;
    }
  }
}

// ---------- edge-conv: y[(n,k),o] = [ctr, nbr-ctr] . W[o,:], track max/min over k + channel sums ----------
// block: 4 points (80 rows) x 64 outputs. 256 thr = 16 tr (5 rows each) x 16 tc (4 o each)
__global__ __launch_bounds__(256) void k_conv(const float* __restrict__ P, int stride, int Ci,
    const float* __restrict__ W, int Oi, const int* __restrict__ idxg,
    float* __restrict__ ymax, float* __restrict__ ymin,
    float* __restrict__ chsum, float* __restrict__ chsq){
  __shared__ int lidx[80];
  __shared__ float ft[80*17];
  __shared__ float wt[16*68];
  __shared__ float red[16*16*4*4];
  int t = threadIdx.x;
  int blk = blockIdx.x;
  int b = blk / (NN/4);
  int n0 = (blk % (NN/4))*4;
  int o0 = blockIdx.y*64;
  if (t < 80) lidx[t] = idxg[((size_t)b*NN + n0 + t/20)*KK + (t%20)];
  int tr = t >> 4, tc = t & 15;
  int twoCi = 2*Ci;
  const float* Pb = P + (size_t)b*NN*stride;
  float acc[5][4];
  #pragma unroll
  for (int i=0;i<5;i++){ acc[i][0]=0.f; acc[i][1]=0.f; acc[i][2]=0.f; acc[i][3]=0.f; }
  int nchunks = (twoCi + 15)/16;
  __syncthreads();
  for (int ch=0; ch<nchunks; ++ch){
    int c0 = ch*16;
    #pragma unroll
    for (int q=0;q<5;q++){
      int e = t + 256*q;
      int r = e >> 4, cc = e & 15;
      int c = c0 + cc;
      int n = n0 + r/20;
      float v = 0.f;
      if (c < Ci) v = Pb[(size_t)n*stride + c];
      else if (c < twoCi){
        int c2 = c - Ci;
        int nbn = lidx[r];
        v = Pb[(size_t)nbn*stride + c2] - Pb[(size_t)n*stride + c2];
      }
      ft[r*17+cc] = v;
    }
    #pragma unroll
    for (int q=0;q<4;q++){
      int e = t + 256*q;
      int oi = e >> 4, cc = e & 15;
      int c = c0 + cc;
      wt[cc*68 + oi] = (c < twoCi) ? W[(size_t)(o0+oi)*twoCi + c] : 0.f;
    }
    __syncthreads();
    #pragma unroll
    for (int j=0;j<16;j++){
      float4 wv = *reinterpret_cast<const float4*>(&wt[j*68 + tc*4]);
      #pragma unroll
      for (int i=0;i<5;i++){
        float a = ft[(tr*5+i)*17 + j];
        acc[i][0] += a*wv.x;
        acc[i][1] += a*wv.y;
        acc[i][2] += a*wv.z;
        acc[i][3] += a*wv.w;
      }
    }
    __syncthreads();
  }
  // stage 1: per-thread stats over its 5 rows (all same point)
  #pragma unroll
  for (int jj=0;jj<4;jj++){
    float y0 = acc[0][jj];
    float mx = y0, mn = y0, s = y0, s2 = y0*y0;
    #pragma unroll
    for (int i=1;i<5;i++){
      float y = acc[i][jj];
      mx = fmaxf(mx,y); mn = fminf(mn,y); s += y; s2 += y*y;
    }
    float* rr = &red[((t*4)+jj)*4];
    rr[0]=mx; rr[1]=mn; rr[2]=s; rr[3]=s2;
  }
  __syncthreads();
  // stage 2: combine 4 tr-rows of same point -> full k=20 stats
  float ssave[4], s2save[4];
  bool isS2 = ((tr & 3) == 0);
  if (isS2){
    int n = n0 + (tr >> 2);
    float omax[4], omin[4];
    #pragma unroll
    for (int jj=0;jj<4;jj++){
      float mx=-3.4e38f, mn=3.4e38f, s=0.f, s2=0.f;
      #pragma unroll
      for (int u=0;u<4;u++){
        const float* rr = &red[((((tr+u)*16+tc)*4)+jj)*4];
        mx = fmaxf(mx, rr[0]); mn = fminf(mn, rr[1]); s += rr[2]; s2 += rr[3];
      }
      omax[jj]=mx; omin[jj]=mn; ssave[jj]=s; s2save[jj]=s2;
    }
    size_t base = ((size_t)b*NN + n)*256 + o0 + tc*4;
    *reinterpret_cast<float4*>(&ymax[base]) = make_float4(omax[0],omax[1],omax[2],omax[3]);
    *reinterpret_cast<float4*>(&ymin[base]) = make_float4(omin[0],omin[1],omin[2],omin[3]);
  }
  __syncthreads();
  if (isS2){
    float* rr  = &red[(((tr*16+tc)*4)+0)*4];
    rr[0]=ssave[0]; rr[1]=ssave[1]; rr[2]=ssave[2]; rr[3]=ssave[3];
    float* rr2 = &red[(((tr*16+tc)*4)+1)*4];
    rr2[0]=s2save[0]; rr2[1]=s2save[1]; rr2[2]=s2save[2]; rr2[3]=s2save[3];
  }
  __syncthreads();
  // stage 3: combine 4 points -> one atomic per (slot,o)
  if (tr == 0){
    int slot = blk & (NSLOT-1);
    #pragma unroll
    for (int jj=0;jj<4;jj++){
      float s = 0.f, s2 = 0.f;
      #pragma unroll
      for (int u=0;u<16;u+=4){
        s  += red[(((u*16+tc)*4)+0)*4 + jj];
        s2 += red[(((u*16+tc)*4)+1)*4 + jj];
      }
      int o = o0 + tc*4 + jj;
      atomicAdd(&chsum[slot*256 + o], s);
      atomicAdd(&chsq[slot*256 + o], s2);
    }
  }
}

// ---------- BN stats finalize (layers) ----------
__global__ __launch_bounds__(256) void k_bnstats(const float* __restrict__ chsum, const float* __restrict__ chsq,
    const float* __restrict__ g, const float* __restrict__ bet,
    float* __restrict__ scl, float* __restrict__ shf, int Oi){
  int o = threadIdx.x;
  if (o >= Oi) return;
  float s=0.f, s2=0.f;
  for (int u=0;u<NSLOT;u++){ s += chsum[u*256+o]; s2 += chsq[u*256+o]; }
  float cnt = (float)(BB*NN*KK);
  float mean = s/cnt;
  float var = s2/cnt - mean*mean;
  float sc = g[o] / sqrtf(var + LEPS);
  scl[o] = sc;
  shf[o] = bet[o] - mean*sc;
}

// ---------- apply BN+LReLU to pooled max/min, write into xc slice ----------
__global__ __launch_bounds__(256) void k_apply(const float* __restrict__ ymax, const float* __restrict__ ymin,
    const float* __restrict__ scl, const float* __restrict__ shf,
    float* __restrict__ xc, int off, int Oi){
  int i = blockIdx.x*256 + threadIdx.x;
  if (i >= BB*NN*Oi) return;
  int o = i & (Oi-1);
  size_t p = (size_t)((unsigned)i / (unsigned)Oi);
  float sc = scl[o];
  float v = (sc >= 0.f) ? ymax[p*256+o] : ymin[p*256+o];
  xc[p*XCCH + off + o] = lrelu(v*sc + shf[o]);
}

// ---------- final 512->1024 conv with per-(b,o) max/min over n-tile + channel sums ----------
// block: b x (32 o) x (256 n). 256 thr = 8 og(4 o) x 32 ng(8 n)
__global__ __launch_bounds__(256) void k_conv5(const float* __restrict__ xc, const float* __restrict__ w5,
    float* __restrict__ pmax, float* __restrict__ pmin, float* __restrict__ psum, float* __restrict__ psq){
  __shared__ float xt[256*33];
  __shared__ float wt[32*36];
  __shared__ float red2[4*32*32];
  int t = threadIdx.x;
  int nbk = blockIdx.x;
  int o0 = blockIdx.y*32;
  int b = blockIdx.z;
  int n0 = nbk*256;
  int og = t >> 5, ng = t & 31;
  float acc[8][4];
  #pragma unroll
  for (int ii=0;ii<8;ii++){ acc[ii][0]=0.f; acc[ii][1]=0.f; acc[ii][2]=0.f; acc[ii][3]=0.f; }
  for (int c0=0;c0<XCCH;c0+=32){
    #pragma unroll
    for (int q=0;q<32;q++){
      int e = t + 256*q;
      int r = e >> 5, cc = e & 31;
      xt[r*33+cc] = xc[((size_t)b*NN + n0 + r)*XCCH + c0 + cc];
    }
    #pragma unroll
    for (int q=0;q<4;q++){
      int e = t + 256*q;
      int oi = e >> 5, cc = e & 31;
      wt[cc*36 + oi] = w5[(size_t)(o0+oi)*XCCH + c0 + cc];
    }
    __syncthreads();
    #pragma unroll
    for (int cc=0;cc<32;cc++){
      float4 wv = *reinterpret_cast<const float4*>(&wt[cc*36 + og*4]);
      #pragma unroll
      for (int ii=0;ii<8;ii++){
        float xv = xt[(ng + 32*ii)*33 + cc];
        acc[ii][0] += xv*wv.x;
        acc[ii][1] += xv*wv.y;
        acc[ii][2] += xv*wv.z;
        acc[ii][3] += xv*wv.w;
      }
    }
    __syncthreads();
  }
  #pragma unroll
  for (int j=0;j<4;j++){
    float y0 = acc[0][j];
    float mx=y0, mn=y0, s=y0, s2=y0*y0;
    #pragma unroll
    for (int ii=1;ii<8;ii++){
      float y = acc[ii][j];
      mx=fmaxf(mx,y); mn=fminf(mn,y); s+=y; s2+=y*y;
    }
    int ol = og*4 + j;
    red2[(0*32+ol)*32+ng]=mx;
    red2[(1*32+ol)*32+ng]=mn;
    red2[(2*32+ol)*32+ng]=s;
    red2[(3*32+ol)*32+ng]=s2;
  }
  __syncthreads();
  if (t < 128){
    int st = t >> 5, ol = t & 31;
    const float* rowp = &red2[(st*32+ol)*32];
    float v = rowp[0];
    if (st == 0){ for (int u=1;u<32;u++) v = fmaxf(v, rowp[u]); }
    else if (st == 1){ for (int u=1;u<32;u++) v = fminf(v, rowp[u]); }
    else { for (int u=1;u<32;u++) v += rowp[u]; }
    size_t iidx = ((size_t)b*1024 + o0 + ol)*8 + nbk;
    if (st==0) pmax[iidx]=v;
    else if (st==1) pmin[iidx]=v;
    else if (st==2) psum[iidx]=v;
    else psq[iidx]=v;
  }
}

__global__ __launch_bounds__(256) void k_stats5(const float* __restrict__ psum, const float* __restrict__ psq,
    const float* __restrict__ g5, const float* __restrict__ b5,
    float* __restrict__ sc5, float* __restrict__ sh5){
  int o = blockIdx.x*256 + threadIdx.x;
  float s=0.f, s2=0.f;
  for (int b=0;b<BB;b++){
    const float* ps = &psum[((size_t)b*1024 + o)*8];
    const float* pq = &psq [((size_t)b*1024 + o)*8];
    #pragma unroll
    for (int u=0;u<8;u++){ s += ps[u]; s2 += pq[u]; }
  }
  float cnt = (float)(BB*NN);
  float mean = s/cnt;
  float var = s2/cnt - mean*mean;
  float sc = g5[o] / sqrtf(var + LEPS);
  sc5[o] = sc;
  sh5[o] = b5[o] - mean*sc;
}

__global__ __launch_bounds__(256) void k_apply5(const float* __restrict__ pmax, const float* __restrict__ pmin,
    const float* __restrict__ sc5, const float* __restrict__ sh5, float* __restrict__ out){
  int i = blockIdx.x*256 + threadIdx.x; // b*1024+o
  int o = i & 1023;
  float sc = sc5[o];
  float v;
  if (sc >= 0.f){
    const float* p = &pmax[(size_t)i*8];
    v = p[0];
    #pragma unroll
    for (int u=1;u<8;u++) v = fmaxf(v, p[u]);
  } else {
    const float* p = &pmin[(size_t)i*8];
    v = p[0];
    #pragma unroll
    for (int u=1;u<8;u++) v = fminf(v, p[u]);
  }
  out[i] = lrelu(v*sc + sh5[o]);
}

extern "C" void kernel_launch(void* const* d_in, const int* in_sizes, int n_in,
                              void* d_out, int out_size, void* d_ws, size_t ws_size,
                              hipStream_t stream){
  const float* x  = (const float*)d_in[0];
  const float* w1 = (const float*)d_in[1];
  const float* g1 = (const float*)d_in[2];
  const float* b1 = (const float*)d_in[3];
  const float* w2 = (const float*)d_in[4];
  const float* g2 = (const float*)d_in[5];
  const float* b2 = (const float*)d_in[6];
  const float* w3 = (const float*)d_in[7];
  const float* g3 = (const float*)d_in[8];
  const float* b3 = (const float*)d_in[9];
  const float* w4 = (const float*)d_in[10];
  const float* g4 = (const float*)d_in[11];
  const float* b4 = (const float*)d_in[12];
  const float* w5 = (const float*)d_in[13];
  const float* g5 = (const float*)d_in[14];
  const float* b5 = (const float*)d_in[15];
  float* out = (float*)d_out;
  float* ws = (float*)d_ws;

  const size_t F_PD   = 0;
  const size_t F_XT0  = F_PD   + (size_t)BB*NN*NN;
  const size_t F_XC   = F_XT0  + (size_t)BB*NN*4;
  const size_t F_YMAX = F_XC   + (size_t)BB*NN*XCCH;
  const size_t F_YMIN = F_YMAX + (size_t)BB*NN*256;
  const size_t F_CHS  = F_YMIN + (size_t)BB*NN*256;
  const size_t F_CHQ  = F_CHS  + (size_t)NSLOT*256;
  const size_t F_SCL  = F_CHQ  + (size_t)NSLOT*256;
  const size_t F_SHF  = F_SCL  + 256;
  const size_t F_SQ   = F_SHF  + 256;
  const size_t F_IDX  = F_SQ   + (size_t)BB*NN;
  const size_t F_PMAX = F_IDX  + (size_t)BB*NN*KK;
  const size_t F_PMIN = F_PMAX + (size_t)BB*1024*8;
  const size_t F_PSUM = F_PMIN + (size_t)BB*1024*8;
  const size_t F_PSQ  = F_PSUM + (size_t)BB*1024*8;
  const size_t F_SC5  = F_PSQ  + (size_t)BB*1024*8;
  const size_t F_SH5  = F_SC5  + 1024;

  float* pd    = ws + F_PD;
  float* xt0   = ws + F_XT0;
  float* xc    = ws + F_XC;
  float* ymax  = ws + F_YMAX;
  float* ymin  = ws + F_YMIN;
  float* chsum = ws + F_CHS;
  float* chsq  = ws + F_CHQ;
  float* scl   = ws + F_SCL;
  float* shf   = ws + F_SHF;
  float* sqb   = ws + F_SQ;
  int*   idxb  = (int*)(ws + F_IDX);
  float* pmax  = ws + F_PMAX;
  float* pmin  = ws + F_PMIN;
  float* psum  = ws + F_PSUM;
  float* psq   = ws + F_PSQ;
  float* sc5   = ws + F_SC5;
  float* sh5   = ws + F_SH5;

  (void)in_sizes; (void)n_in; (void)out_size; (void)ws_size;

  k_transpose<<<64, 256, 0, stream>>>(x, xt0);

  struct LayerP { const float* P; int stride; int Ci; int CiD; const float* W; const float* g; const float* b; int Oi; int off; };
  LayerP L[4] = {
    { xt0,    4,   3,   4,   w1, g1, b1,  64, 0   },
    { xc,     512, 64,  64,  w2, g2, b2,  64, 64  },
    { xc+64,  512, 64,  64,  w3, g3, b3, 128, 128 },
    { xc+128, 512, 128, 128, w4, g4, b4, 256, 256 },
  };

  for (int l=0; l<4; ++l){
    k_sq<<<64, 256, 0, stream>>>(L[l].P, L[l].stride, L[l].CiD, sqb);
    k_dist<<<dim3(16,16,8), 256, 0, stream>>>(L[l].P, L[l].stride, L[l].CiD, sqb, pd);
    k_topk<<<BB*NN, 256, 0, stream>>>(pd, idxb);
    hipMemsetAsync(chsum, 0, (size_t)NSLOT*256*2*sizeof(float), stream);
    k_conv<<<dim3(BB*NN/4, L[l].Oi/64), 256, 0, stream>>>(L[l].P, L[l].stride, L[l].Ci, L[l].W, L[l].Oi,
                                                          idxb, ymax, ymin, chsum, chsq);
    k_bnstats<<<1, 256, 0, stream>>>(chsum, chsq, L[l].g, L[l].b, scl, shf, L[l].Oi);
    k_apply<<<(BB*NN*L[l].Oi + 255)/256, 256, 0, stream>>>(ymax, ymin, scl, shf, xc, L[l].off, L[l].Oi);
  }

  k_conv5<<<dim3(8, 32, BB), 256, 0, stream>>>(xc, w5, pmax, pmin, psum, psq);
  k_stats5<<<4, 256, 0, stream>>>(psum, psq, g5, b5, sc5, sh5);
  k_apply5<<<(BB*1024)/256, 256, 0, stream>>>(pmax, pmin, sc5, sh5, out);
}

// Round 3
// 2238.721 us; speedup vs baseline: 1.4848x; 1.4848x over previous
//
#include <hip/hip_runtime.h>
#include <hip/hip_bf16.h>
#include <math.h>

#define BB 8
#define NN 2048
#define KK 20
#define XCCH 512
#define NSLOT 64
#define LEPS 1e-5f

typedef __attribute__((ext_vector_type(8))) short s8v;
typedef __attribute__((ext_vector_type(4))) float f32x4;

__device__ __forceinline__ float lrelu(float x){ return x >= 0.f ? x : 0.2f*x; }

__device__ __forceinline__ s8v bsub8(s8v a, s8v b){
  union U { s8v s; __hip_bfloat162 h[4]; } A, B, R;
  A.s = a; B.s = b;
  #pragma unroll
  for (int i=0;i<4;i++) R.h[i] = __hsub2(A.h[i], B.h[i]);
  return R.s;
}

// ---------- transpose x (B,3,N) -> xt0 (B*N,4) fp32 ----------
__global__ __launch_bounds__(256) void k_transpose(const float* __restrict__ x, float* __restrict__ xt){
  int i = blockIdx.x*256 + threadIdx.x;
  if (i >= BB*NN) return;
  int b = i >> 11, n = i & (NN-1);
  float4 v;
  v.x = x[(b*3+0)*NN + n];
  v.y = x[(b*3+1)*NN + n];
  v.z = x[(b*3+2)*NN + n];
  v.w = 0.f;
  reinterpret_cast<float4*>(xt)[i] = v;
}

// ---------- weight fp32 -> bf16 with K padding ----------
__global__ __launch_bounds__(256) void k_cvtw(const float* __restrict__ W, __hip_bfloat16* __restrict__ Wb,
                                              int C, int Cpad, int total){
  int i = blockIdx.x*256 + threadIdx.x;
  if (i >= total) return;
  int o = i / Cpad, c = i - o*Cpad;
  Wb[i] = (c < C) ? __float2bfloat16(W[o*C + c]) : __float2bfloat16(0.f);
}

// ---------- squared norms ----------
__global__ __launch_bounds__(256) void k_sq(const float* __restrict__ P, int stride, int Ci, float* __restrict__ sq){
  int i = blockIdx.x*256 + threadIdx.x;
  if (i >= BB*NN) return;
  const float* p = P + (size_t)i*stride;
  float s = 0.f;
  for (int c = 0; c < Ci; ++c){ float v = p[c]; s += v*v; }
  sq[i] = s;
}

// ---------- pairwise score pd = 2*dot - sq_n - sq_m (fp32) ----------
__global__ __launch_bounds__(256) void k_dist(const float* __restrict__ P, int stride, int Ci,
                                              const float* __restrict__ sq, float* __restrict__ pd){
  __shared__ float At[128*17];
  __shared__ float Bt[128*17];
  int b = blockIdx.z;
  int n0 = blockIdx.y*128, m0 = blockIdx.x*128;
  int t = threadIdx.x;
  int ty = t >> 4, tx = t & 15;
  float acc[8][8];
  #pragma unroll
  for (int i=0;i<8;i++)
    #pragma unroll
    for (int j=0;j<8;j++) acc[i][j]=0.f;
  const float* Pb = P + (size_t)b*NN*stride;
  for (int c0 = 0; c0 < Ci; c0 += 16){
    #pragma unroll
    for (int q = 0; q < 8; ++q){
      int e = t + 256*q;
      int r = e >> 4, cc = e & 15;
      int c = c0 + cc;
      bool ok = (c < Ci);
      At[r*17+cc] = ok ? Pb[(size_t)(n0+r)*stride + c] : 0.f;
      Bt[r*17+cc] = ok ? Pb[(size_t)(m0+r)*stride + c] : 0.f;
    }
    __syncthreads();
    #pragma unroll
    for (int j = 0; j < 16; ++j){
      float a[8], bv[8];
      #pragma unroll
      for (int i=0;i<8;i++) a[i]  = At[(ty*8+i)*17 + j];
      #pragma unroll
      for (int i=0;i<8;i++) bv[i] = Bt[(tx*8+i)*17 + j];
      #pragma unroll
      for (int i=0;i<8;i++)
        #pragma unroll
        for (int jj=0;jj<8;jj++) acc[i][jj] += a[i]*bv[jj];
    }
    __syncthreads();
  }
  float sqn[8], sqm[8];
  #pragma unroll
  for (int i=0;i<8;i++) sqn[i] = sq[b*NN + n0 + ty*8 + i];
  #pragma unroll
  for (int i=0;i<8;i++) sqm[i] = sq[b*NN + m0 + tx*8 + i];
  #pragma unroll
  for (int i=0;i<8;i++){
    size_t base = ((size_t)b*NN + n0+ty*8+i)*NN + m0 + tx*8;
    float4 v0, v1;
    v0.x = 2.f*acc[i][0] - sqn[i] - sqm[0];
    v0.y = 2.f*acc[i][1] - sqn[i] - sqm[1];
    v0.z = 2.f*acc[i][2] - sqn[i] - sqm[2];
    v0.w = 2.f*acc[i][3] - sqn[i] - sqm[3];
    v1.x = 2.f*acc[i][4] - sqn[i] - sqm[4];
    v1.y = 2.f*acc[i][5] - sqn[i] - sqm[5];
    v1.z = 2.f*acc[i][6] - sqn[i] - sqm[6];
    v1.w = 2.f*acc[i][7] - sqn[i] - sqm[7];
    reinterpret_cast<float4*>(pd + base)[0] = v0;
    reinterpret_cast<float4*>(pd + base)[1] = v1;
  }
}

// ---------- top-20 per row ----------
__global__ __launch_bounds__(256) void k_topk(const float* __restrict__ pd, int* __restrict__ idxo){
  __shared__ float wvs[4];
  __shared__ int wms[4];
  __shared__ int gb;
  int bid = blockIdx.x;
  int t = threadIdx.x;
  const float* row = pd + (size_t)bid*NN;
  float r[8];
  #pragma unroll
  for (int j=0;j<8;j++) r[j] = row[t + 256*j];
  int* o = idxo + bid*KK;
  for (int it=0; it<KK; ++it){
    float bv = r[0]; int bm = t;
    #pragma unroll
    for (int j=1;j<8;j++){
      if (r[j] > bv){ bv = r[j]; bm = t + 256*j; }
    }
    #pragma unroll
    for (int off=32; off>0; off>>=1){
      float ov = __shfl_down(bv, off);
      int om = __shfl_down(bm, off);
      if (ov > bv || (ov == bv && om < bm)){ bv = ov; bm = om; }
    }
    if ((t & 63) == 0){ wvs[t>>6] = bv; wms[t>>6] = bm; }
    __syncthreads();
    if (t == 0){
      float fv = wvs[0]; int fm = wms[0];
      for (int w2=1; w2<4; ++w2){
        if (wvs[w2] > fv || (wvs[w2] == fv && wms[w2] < fm)){ fv = wvs[w2]; fm = wms[w2]; }
      }
      o[it] = fm;
      gb = fm;
    }
    __syncthreads();
    int bm2 = gb;
    #pragma unroll
    for (int j=0;j<8;j++){
      if (bm2 == t + 256*j) r[j] = -3.4e38f;
    }
  }
}

// ---------- fp32 edge-conv (layers 1-3; knn-feeding, needs fp32 accuracy) ----------
// block: 4 points (80 rows) x 64 outputs. 256 thr = 16 tr (5 rows each) x 16 tc (4 o each)
__global__ __launch_bounds__(256) void k_conv(const float* __restrict__ P, int stride, int Ci,
    const float* __restrict__ W, int Oi, const int* __restrict__ idxg,
    float* __restrict__ ymax, float* __restrict__ ymin,
    float* __restrict__ chsum, float* __restrict__ chsq){
  __shared__ int lidx[80];
  __shared__ float ft[80*17];
  __shared__ float wt[16*68];
  __shared__ float red[16*16*4*4];
  int t = threadIdx.x;
  int blk = blockIdx.x;
  int b = blk / (NN/4);
  int n0 = (blk % (NN/4))*4;
  int o0 = blockIdx.y*64;
  if (t < 80) lidx[t] = idxg[((size_t)b*NN + n0 + t/20)*KK + (t%20)];
  int tr = t >> 4, tc = t & 15;
  int twoCi = 2*Ci;
  const float* Pb = P + (size_t)b*NN*stride;
  float acc[5][4];
  #pragma unroll
  for (int i=0;i<5;i++){ acc[i][0]=0.f; acc[i][1]=0.f; acc[i][2]=0.f; acc[i][3]=0.f; }
  int nchunks = (twoCi + 15)/16;
  __syncthreads();
  for (int ch=0; ch<nchunks; ++ch){
    int c0 = ch*16;
    #pragma unroll
    for (int q=0;q<5;q++){
      int e = t + 256*q;
      int r = e >> 4, cc = e & 15;
      int c = c0 + cc;
      int n = n0 + r/20;
      float v = 0.f;
      if (c < Ci) v = Pb[(size_t)n*stride + c];
      else if (c < twoCi){
        int c2 = c - Ci;
        int nbn = lidx[r];
        v = Pb[(size_t)nbn*stride + c2] - Pb[(size_t)n*stride + c2];
      }
      ft[r*17+cc] = v;
    }
    #pragma unroll
    for (int q=0;q<4;q++){
      int e = t + 256*q;
      int oi = e >> 4, cc = e & 15;
      int c = c0 + cc;
      wt[cc*68 + oi] = (c < twoCi) ? W[(size_t)(o0+oi)*twoCi + c] : 0.f;
    }
    __syncthreads();
    #pragma unroll
    for (int j=0;j<16;j++){
      float4 wv = *reinterpret_cast<const float4*>(&wt[j*68 + tc*4]);
      #pragma unroll
      for (int i=0;i<5;i++){
        float a = ft[(tr*5+i)*17 + j];
        acc[i][0] += a*wv.x;
        acc[i][1] += a*wv.y;
        acc[i][2] += a*wv.z;
        acc[i][3] += a*wv.w;
      }
    }
    __syncthreads();
  }
  #pragma unroll
  for (int jj=0;jj<4;jj++){
    float y0 = acc[0][jj];
    float mx = y0, mn = y0, s = y0, s2 = y0*y0;
    #pragma unroll
    for (int i=1;i<5;i++){
      float y = acc[i][jj];
      mx = fmaxf(mx,y); mn = fminf(mn,y); s += y; s2 += y*y;
    }
    float* rr = &red[((t*4)+jj)*4];
    rr[0]=mx; rr[1]=mn; rr[2]=s; rr[3]=s2;
  }
  __syncthreads();
  float ssave[4], s2save[4];
  bool isS2 = ((tr & 3) == 0);
  if (isS2){
    int n = n0 + (tr >> 2);
    float omax[4], omin[4];
    #pragma unroll
    for (int jj=0;jj<4;jj++){
      float mx=-3.4e38f, mn=3.4e38f, s=0.f, s2=0.f;
      #pragma unroll
      for (int u=0;u<4;u++){
        const float* rr = &red[((((tr+u)*16+tc)*4)+jj)*4];
        mx = fmaxf(mx, rr[0]); mn = fminf(mn, rr[1]); s += rr[2]; s2 += rr[3];
      }
      omax[jj]=mx; omin[jj]=mn; ssave[jj]=s; s2save[jj]=s2;
    }
    size_t base = ((size_t)b*NN + n)*256 + o0 + tc*4;
    *reinterpret_cast<float4*>(&ymax[base]) = make_float4(omax[0],omax[1],omax[2],omax[3]);
    *reinterpret_cast<float4*>(&ymin[base]) = make_float4(omin[0],omin[1],omin[2],omin[3]);
  }
  __syncthreads();
  if (isS2){
    float* rr  = &red[(((tr*16+tc)*4)+0)*4];
    rr[0]=ssave[0]; rr[1]=ssave[1]; rr[2]=ssave[2]; rr[3]=ssave[3];
    float* rr2 = &red[(((tr*16+tc)*4)+1)*4];
    rr2[0]=s2save[0]; rr2[1]=s2save[1]; rr2[2]=s2save[2]; rr2[3]=s2save[3];
  }
  __syncthreads();
  if (tr == 0){
    int slot = blk & (NSLOT-1);
    #pragma unroll
    for (int jj=0;jj<4;jj++){
      float s = 0.f, s2 = 0.f;
      #pragma unroll
      for (int u=0;u<16;u+=4){
        s  += red[(((u*16+tc)*4)+0)*4 + jj];
        s2 += red[(((u*16+tc)*4)+1)*4 + jj];
      }
      int o = o0 + tc*4 + jj;
      atomicAdd(&chsum[slot*256 + o], s);
      atomicAdd(&chsq[slot*256 + o], s2);
    }
  }
}

// ---------- MFMA edge-conv (layer 4 only; output never feeds knn) ----------
__global__ __launch_bounds__(256) void k_convm(
    const __hip_bfloat16* __restrict__ PB, int stride, int Ci,
    const __hip_bfloat16* __restrict__ Wb, int nchunk,
    const int* __restrict__ idxg,
    float* __restrict__ ymax, float* __restrict__ ymin,
    float* __restrict__ chsum, float* __restrict__ chsq)
{
  __shared__ __align__(16) char smem[40960];
  __hip_bfloat16* As = (__hip_bfloat16*)smem;       // [320][40]
  float* redmx = (float*)smem;                       // [80 gq][64 col]
  float* redmn = (float*)(smem + 20480);
  __shared__ int lidx[320];
  int t = threadIdx.x;
  int w = t >> 6, lane = t & 63, m = lane & 15, quad = lane >> 4;
  int p0 = blockIdx.x * 16;
  int b  = p0 >> 11;
  int o0 = blockIdx.y * 64;
  int Kpad = nchunk * 32;
  for (int q = t; q < 320; q += 256) lidx[q] = idxg[p0*KK + q];
  f32x4 acc[20];
  #pragma unroll
  for (int s=0;s<20;s++){ f32x4 z = {0.f,0.f,0.f,0.f}; acc[s] = z; }
  __syncthreads();

  const __hip_bfloat16* wrow = Wb + (size_t)(o0 + w*16 + m)*Kpad + quad*8;

  unsigned offn[5], offnb[5]; int lo[5];
  #pragma unroll
  for (int q=0;q<5;q++){
    int s = t + 256*q;
    int rr = s >> 2, seg = s & 3;
    int pp = (rr*6554) >> 17;                 // rr/20
    int n_g  = p0 + pp;
    int nb_g = (b<<11) + lidx[rr];
    offn[q]  = (unsigned)n_g*stride  + seg*8;
    offnb[q] = (unsigned)nb_g*stride + seg*8;
    lo[q] = rr*40 + seg*8;
  }
  int cch = Ci >> 5;
  for (int ch=0; ch<nchunk; ++ch){
    int c0 = ch*32;
    if (ch < cch){
      #pragma unroll
      for (int q=0;q<5;q++)
        *(s8v*)&As[lo[q]] = *(const s8v*)&PB[offn[q] + c0];
    } else {
      int c2 = c0 - Ci;
      #pragma unroll
      for (int q=0;q<5;q++){
        s8v a  = *(const s8v*)&PB[offnb[q] + c2];
        s8v bb = *(const s8v*)&PB[offn[q]  + c2];
        *(s8v*)&As[lo[q]] = bsub8(a, bb);
      }
    }
    __syncthreads();
    s8v bf = *(const s8v*)(wrow + c0);
    #pragma unroll
    for (int s=0;s<20;s++){
      s8v af = *(const s8v*)&As[(s*16+m)*40 + quad*8];
      acc[s] = __builtin_amdgcn_mfma_f32_16x16x32_bf16(af, bf, acc[s], 0, 0, 0);
    }
    __syncthreads();
  }

  float sm = 0.f, sq = 0.f;
  #pragma unroll
  for (int s=0;s<20;s++){
    f32x4 a = acc[s];
    float mx = fmaxf(fmaxf(a.x,a.y), fmaxf(a.z,a.w));
    float mn = fminf(fminf(a.x,a.y), fminf(a.z,a.w));
    sm += a.x + a.y + a.z + a.w;
    sq += a.x*a.x + a.y*a.y + a.z*a.z + a.w*a.w;
    int gq = s*4 + quad;
    redmx[gq*64 + w*16 + m] = mx;
    redmn[gq*64 + w*16 + m] = mn;
  }
  sm += __shfl_xor(sm, 16); sq += __shfl_xor(sq, 16);
  sm += __shfl_xor(sm, 32); sq += __shfl_xor(sq, 32);
  if (quad == 0){
    int o = o0 + w*16 + m;
    int slot = blockIdx.x & (NSLOT-1);
    atomicAdd(&chsum[slot*256 + o], sm);
    atomicAdd(&chsq [slot*256 + o], sq);
  }
  __syncthreads();
  #pragma unroll
  for (int q=0;q<4;q++){
    int i = t + 256*q;
    int pp = i >> 6, col = i & 63;
    float mx = redmx[(pp*5)*64 + col];
    float mn = redmn[(pp*5)*64 + col];
    #pragma unroll
    for (int u=1;u<5;u++){
      mx = fmaxf(mx, redmx[(pp*5+u)*64 + col]);
      mn = fminf(mn, redmn[(pp*5+u)*64 + col]);
    }
    size_t base = ((size_t)(p0+pp))*256 + o0 + col;
    ymax[base] = mx;
    ymin[base] = mn;
  }
}

// ---------- BN stats finalize ----------
__global__ __launch_bounds__(256) void k_bnstats(const float* __restrict__ chsum, const float* __restrict__ chsq,
    const float* __restrict__ g, const float* __restrict__ bet,
    float* __restrict__ scl, float* __restrict__ shf, int Oi){
  int o = threadIdx.x;
  if (o >= Oi) return;
  float s=0.f, s2=0.f;
  for (int u=0;u<NSLOT;u++){ s += chsum[u*256+o]; s2 += chsq[u*256+o]; }
  float cnt = (float)(BB*NN*KK);
  float mean = s/cnt;
  float var = s2/cnt - mean*mean;
  float sc = g[o] / sqrtf(var + LEPS);
  scl[o] = sc;
  shf[o] = bet[o] - mean*sc;
}

// ---------- apply BN+LReLU, write fp32 xc + bf16 xcb ----------
__global__ __launch_bounds__(256) void k_apply(const float* __restrict__ ymax, const float* __restrict__ ymin,
    const float* __restrict__ scl, const float* __restrict__ shf,
    float* __restrict__ xc, __hip_bfloat16* __restrict__ xcb, int off, int Oi){
  int i = blockIdx.x*256 + threadIdx.x;
  if (i >= BB*NN*Oi) return;
  int o = i & (Oi-1);
  size_t p = (size_t)((unsigned)i / (unsigned)Oi);
  float sc = scl[o];
  float v = (sc >= 0.f) ? ymax[p*256+o] : ymin[p*256+o];
  float r = lrelu(v*sc + shf[o]);
  xc [p*XCCH + off + o] = r;
  xcb[p*XCCH + off + o] = __float2bfloat16(r);
}

// ---------- MFMA conv5 ----------
__global__ __launch_bounds__(256) void k_conv5m(const __hip_bfloat16* __restrict__ xcb,
    const __hip_bfloat16* __restrict__ w5b,
    float* __restrict__ pmax, float* __restrict__ pmin,
    float* __restrict__ psum, float* __restrict__ psq)
{
  int t = threadIdx.x, w = t >> 6, lane = t & 63, m = lane & 15, quad = lane >> 4;
  int nbk = blockIdx.x, b = blockIdx.z;
  int o0 = blockIdx.y * 64;
  int n0 = nbk * 256;
  const __hip_bfloat16* arow = xcb + (size_t)(b*NN + n0 + m)*XCCH + quad*8;
  const __hip_bfloat16* brow = w5b + (size_t)(o0 + w*16 + m)*XCCH + quad*8;
  f32x4 acc[16];
  #pragma unroll
  for (int s=0;s<16;s++){ f32x4 z = {0.f,0.f,0.f,0.f}; acc[s] = z; }
  for (int ch=0; ch<16; ++ch){
    int c0 = ch*32;
    s8v bf = *(const s8v*)(brow + c0);
    #pragma unroll
    for (int s=0;s<16;s++){
      s8v af = *(const s8v*)(arow + (size_t)s*16*XCCH + c0);
      acc[s] = __builtin_amdgcn_mfma_f32_16x16x32_bf16(af, bf, acc[s], 0, 0, 0);
    }
  }
  float mx = -3.4e38f, mn = 3.4e38f, sm = 0.f, sq = 0.f;
  #pragma unroll
  for (int s=0;s<16;s++){
    f32x4 a = acc[s];
    mx = fmaxf(mx, fmaxf(fmaxf(a.x,a.y), fmaxf(a.z,a.w)));
    mn = fminf(mn, fminf(fminf(a.x,a.y), fminf(a.z,a.w)));
    sm += a.x + a.y + a.z + a.w;
    sq += a.x*a.x + a.y*a.y + a.z*a.z + a.w*a.w;
  }
  #pragma unroll
  for (int off=16; off<=32; off<<=1){
    mx = fmaxf(mx, __shfl_xor(mx, off));
    mn = fminf(mn, __shfl_xor(mn, off));
    sm += __shfl_xor(sm, off);
    sq += __shfl_xor(sq, off);
  }
  if (quad == 0){
    size_t ii = ((size_t)b*1024 + o0 + w*16 + m)*8 + nbk;
    pmax[ii] = mx; pmin[ii] = mn; psum[ii] = sm; psq[ii] = sq;
  }
}

__global__ __launch_bounds__(256) void k_stats5(const float* __restrict__ psum, const float* __restrict__ psq,
    const float* __restrict__ g5, const float* __restrict__ b5,
    float* __restrict__ sc5, float* __restrict__ sh5){
  int o = blockIdx.x*256 + threadIdx.x;
  float s=0.f, s2=0.f;
  for (int b=0;b<BB;b++){
    const float* ps = &psum[((size_t)b*1024 + o)*8];
    const float* pq = &psq [((size_t)b*1024 + o)*8];
    #pragma unroll
    for (int u=0;u<8;u++){ s += ps[u]; s2 += pq[u]; }
  }
  float cnt = (float)(BB*NN);
  float mean = s/cnt;
  float var = s2/cnt - mean*mean;
  float sc = g5[o] / sqrtf(var + LEPS);
  sc5[o] = sc;
  sh5[o] = b5[o] - mean*sc;
}

__global__ __launch_bounds__(256) void k_apply5(const float* __restrict__ pmax, const float* __restrict__ pmin,
    const float* __restrict__ sc5, const float* __restrict__ sh5, float* __restrict__ out){
  int i = blockIdx.x*256 + threadIdx.x;
  int o = i & 1023;
  float sc = sc5[o];
  float v;
  if (sc >= 0.f){
    const float* p = &pmax[(size_t)i*8];
    v = p[0];
    #pragma unroll
    for (int u=1;u<8;u++) v = fmaxf(v, p[u]);
  } else {
    const float* p = &pmin[(size_t)i*8];
    v = p[0];
    #pragma unroll
    for (int u=1;u<8;u++) v = fminf(v, p[u]);
  }
  out[i] = lrelu(v*sc + sh5[o]);
}

extern "C" void kernel_launch(void* const* d_in, const int* in_sizes, int n_in,
                              void* d_out, int out_size, void* d_ws, size_t ws_size,
                              hipStream_t stream){
  const float* x  = (const float*)d_in[0];
  const float* w1 = (const float*)d_in[1];
  const float* g1 = (const float*)d_in[2];
  const float* b1 = (const float*)d_in[3];
  const float* w2 = (const float*)d_in[4];
  const float* g2 = (const float*)d_in[5];
  const float* b2 = (const float*)d_in[6];
  const float* w3 = (const float*)d_in[7];
  const float* g3 = (const float*)d_in[8];
  const float* b3 = (const float*)d_in[9];
  const float* w4 = (const float*)d_in[10];
  const float* g4 = (const float*)d_in[11];
  const float* b4 = (const float*)d_in[12];
  const float* w5 = (const float*)d_in[13];
  const float* g5 = (const float*)d_in[14];
  const float* b5 = (const float*)d_in[15];
  float* out = (float*)d_out;
  float* ws = (float*)d_ws;

  const size_t F_PD   = 0;
  const size_t F_XT0  = F_PD   + (size_t)BB*NN*NN;
  const size_t F_XC   = F_XT0  + (size_t)BB*NN*4;
  const size_t F_CHS  = F_XC   + (size_t)BB*NN*XCCH;
  const size_t F_CHQ  = F_CHS  + (size_t)NSLOT*256;
  const size_t F_SCL  = F_CHQ  + (size_t)NSLOT*256;
  const size_t F_SHF  = F_SCL  + 256;
  const size_t F_SQ   = F_SHF  + 256;
  const size_t F_IDX  = F_SQ   + (size_t)BB*NN;
  const size_t F_PMAX = F_IDX  + (size_t)BB*NN*KK;
  const size_t F_PMIN = F_PMAX + (size_t)BB*1024*8;
  const size_t F_PSUM = F_PMIN + (size_t)BB*1024*8;
  const size_t F_PSQ  = F_PSUM + (size_t)BB*1024*8;
  const size_t F_SC5  = F_PSQ  + (size_t)BB*1024*8;
  const size_t F_SH5  = F_SC5  + 1024;
  const size_t F_XCB  = F_SH5  + 1024;
  const size_t F_WB   = F_XCB  + (size_t)BB*NN*XCCH/2;

  float* pd    = ws + F_PD;
  float* ymax  = pd + (size_t)16*1024*1024;   // alias into pd (pd dead after k_topk)
  float* ymin  = pd + (size_t)21*1024*1024;
  float* xt0   = ws + F_XT0;
  float* xc    = ws + F_XC;
  float* chsum = ws + F_CHS;
  float* chsq  = ws + F_CHQ;
  float* scl   = ws + F_SCL;
  float* shf   = ws + F_SHF;
  float* sqb   = ws + F_SQ;
  int*   idxb  = (int*)(ws + F_IDX);
  float* pmax  = ws + F_PMAX;
  float* pmin  = ws + F_PMIN;
  float* psum  = ws + F_PSUM;
  float* psq   = ws + F_PSQ;
  float* sc5   = ws + F_SC5;
  float* sh5   = ws + F_SH5;
  __hip_bfloat16* xcb = (__hip_bfloat16*)(ws + F_XCB);
  __hip_bfloat16* wb  = (__hip_bfloat16*)(ws + F_WB);
  __hip_bfloat16* w4b = wb;            // 256x256
  __hip_bfloat16* w5b = wb + 65536;    // 1024x512

  (void)in_sizes; (void)n_in; (void)out_size; (void)ws_size;

  k_transpose<<<64, 256, 0, stream>>>(x, xt0);
  k_cvtw<<<(65536+255)/256,  256, 0, stream>>>(w4, w4b, 256, 256, 65536);
  k_cvtw<<<(524288+255)/256, 256, 0, stream>>>(w5, w5b, 512, 512, 524288);

  struct LayerP { const float* P; int stride; int Ci; int CiD; const float* W; const float* g; const float* b; int Oi; int off; };
  LayerP L[4] = {
    { xt0,    4,   3,   4,   w1, g1, b1,  64, 0   },
    { xc,     512, 64,  64,  w2, g2, b2,  64, 64  },
    { xc+64,  512, 64,  64,  w3, g3, b3, 128, 128 },
    { xc+128, 512, 128, 128, w4, g4, b4, 256, 256 },
  };

  for (int l=0; l<4; ++l){
    k_sq<<<64, 256, 0, stream>>>(L[l].P, L[l].stride, L[l].CiD, sqb);
    k_dist<<<dim3(16,16,8), 256, 0, stream>>>(L[l].P, L[l].stride, L[l].CiD, sqb, pd);
    k_topk<<<BB*NN, 256, 0, stream>>>(pd, idxb);
    hipMemsetAsync(chsum, 0, (size_t)NSLOT*256*2*sizeof(float), stream);
    if (l < 3){
      k_conv<<<dim3(BB*NN/4, L[l].Oi/64), 256, 0, stream>>>(L[l].P, L[l].stride, L[l].Ci, L[l].W, L[l].Oi,
                                                            idxb, ymax, ymin, chsum, chsq);
    } else {
      k_convm<<<dim3(BB*NN/16, 4), 256, 0, stream>>>(xcb+128, XCCH, 128, w4b, 8,
                                                     idxb, ymax, ymin, chsum, chsq);
    }
    k_bnstats<<<1, 256, 0, stream>>>(chsum, chsq, L[l].g, L[l].b, scl, shf, L[l].Oi);
    k_apply<<<(BB*NN*L[l].Oi + 255)/256, 256, 0, stream>>>(ymax, ymin, scl, shf, xc, xcb, L[l].off, L[l].Oi);
  }

  k_conv5m<<<dim3(8, 16, BB), 256, 0, stream>>>(xcb, w5b, pmax, pmin, psum, psq);
  k_stats5<<<4, 256, 0, stream>>>(psum, psq, g5, b5, sc5, sh5);
  k_apply5<<<(BB*1024)/256, 256, 0, stream>>>(pmax, pmin, sc5, sh5, out);
}

// Round 4
// 1854.687 us; speedup vs baseline: 1.7923x; 1.2071x over previous
//
#include <hip/hip_runtime.h>
#include <hip/hip_bf16.h>
#include <math.h>

#define BB 8
#define NN 2048
#define KK 20
#define XCCH 512
#define NSLOT 64
#define LEPS 1e-5f

typedef __attribute__((ext_vector_type(8))) short s8v;
typedef __attribute__((ext_vector_type(4))) float f32x4;

__device__ __forceinline__ float lrelu(float x){ return x >= 0.f ? x : 0.2f*x; }

__device__ __forceinline__ s8v bsub8(s8v a, s8v b){
  union U { s8v s; __hip_bfloat162 h[4]; } A, B, R;
  A.s = a; B.s = b;
  #pragma unroll
  for (int i=0;i<4;i++) R.h[i] = __hsub2(A.h[i], B.h[i]);
  return R.s;
}

// ---------- transpose x (B,3,N) -> xt0 (B*N,4) fp32 ----------
__global__ __launch_bounds__(256) void k_transpose(const float* __restrict__ x, float* __restrict__ xt){
  int i = blockIdx.x*256 + threadIdx.x;
  if (i >= BB*NN) return;
  int b = i >> 11, n = i & (NN-1);
  float4 v;
  v.x = x[(b*3+0)*NN + n];
  v.y = x[(b*3+1)*NN + n];
  v.z = x[(b*3+2)*NN + n];
  v.w = 0.f;
  reinterpret_cast<float4*>(xt)[i] = v;
}

// ---------- weight fp32 -> bf16 slice with K padding ----------
// Wb[o*Cpad+c] = (c<Ccnt) ? W[o*Cs + coff + c] : 0
__global__ __launch_bounds__(256) void k_cvtw(const float* __restrict__ W, __hip_bfloat16* __restrict__ Wb,
                                              int Cs, int coff, int Ccnt, int Cpad, int total){
  int i = blockIdx.x*256 + threadIdx.x;
  if (i >= total) return;
  int o = i / Cpad, c = i - o*Cpad;
  Wb[i] = (c < Ccnt) ? __float2bfloat16(W[(size_t)o*Cs + coff + c]) : __float2bfloat16(0.f);
}

// ---------- squared norms ----------
__global__ __launch_bounds__(256) void k_sq(const float* __restrict__ P, int stride, int Ci, float* __restrict__ sq){
  int i = blockIdx.x*256 + threadIdx.x;
  if (i >= BB*NN) return;
  const float* p = P + (size_t)i*stride;
  float s = 0.f;
  for (int c = 0; c < Ci; ++c){ float v = p[c]; s += v*v; }
  sq[i] = s;
}

// ---------- pairwise score pd = 2*dot - sq_n - sq_m (fp32) ----------
__global__ __launch_bounds__(256) void k_dist(const float* __restrict__ P, int stride, int Ci,
                                              const float* __restrict__ sq, float* __restrict__ pd){
  __shared__ float At[128*17];
  __shared__ float Bt[128*17];
  int b = blockIdx.z;
  int n0 = blockIdx.y*128, m0 = blockIdx.x*128;
  int t = threadIdx.x;
  int ty = t >> 4, tx = t & 15;
  float acc[8][8];
  #pragma unroll
  for (int i=0;i<8;i++)
    #pragma unroll
    for (int j=0;j<8;j++) acc[i][j]=0.f;
  const float* Pb = P + (size_t)b*NN*stride;
  for (int c0 = 0; c0 < Ci; c0 += 16){
    #pragma unroll
    for (int q = 0; q < 8; ++q){
      int e = t + 256*q;
      int r = e >> 4, cc = e & 15;
      int c = c0 + cc;
      bool ok = (c < Ci);
      At[r*17+cc] = ok ? Pb[(size_t)(n0+r)*stride + c] : 0.f;
      Bt[r*17+cc] = ok ? Pb[(size_t)(m0+r)*stride + c] : 0.f;
    }
    __syncthreads();
    #pragma unroll
    for (int j = 0; j < 16; ++j){
      float a[8], bv[8];
      #pragma unroll
      for (int i=0;i<8;i++) a[i]  = At[(ty*8+i)*17 + j];
      #pragma unroll
      for (int i=0;i<8;i++) bv[i] = Bt[(tx*8+i)*17 + j];
      #pragma unroll
      for (int i=0;i<8;i++)
        #pragma unroll
        for (int jj=0;jj<8;jj++) acc[i][jj] += a[i]*bv[jj];
    }
    __syncthreads();
  }
  float sqn[8], sqm[8];
  #pragma unroll
  for (int i=0;i<8;i++) sqn[i] = sq[b*NN + n0 + ty*8 + i];
  #pragma unroll
  for (int i=0;i<8;i++) sqm[i] = sq[b*NN + m0 + tx*8 + i];
  #pragma unroll
  for (int i=0;i<8;i++){
    size_t base = ((size_t)b*NN + n0+ty*8+i)*NN + m0 + tx*8;
    float4 v0, v1;
    v0.x = 2.f*acc[i][0] - sqn[i] - sqm[0];
    v0.y = 2.f*acc[i][1] - sqn[i] - sqm[1];
    v0.z = 2.f*acc[i][2] - sqn[i] - sqm[2];
    v0.w = 2.f*acc[i][3] - sqn[i] - sqm[3];
    v1.x = 2.f*acc[i][4] - sqn[i] - sqm[4];
    v1.y = 2.f*acc[i][5] - sqn[i] - sqm[5];
    v1.z = 2.f*acc[i][6] - sqn[i] - sqm[6];
    v1.w = 2.f*acc[i][7] - sqn[i] - sqm[7];
    reinterpret_cast<float4*>(pd + base)[0] = v0;
    reinterpret_cast<float4*>(pd + base)[1] = v1;
  }
}

// ---------- top-20 per row: one wave per row, no barriers ----------
__global__ __launch_bounds__(256) void k_topk(const float* __restrict__ pd, int* __restrict__ idxo){
  int t = threadIdx.x;
  int l = t & 63;
  int row = blockIdx.x*4 + (t >> 6);
  const float4* rp = (const float4*)(pd + (size_t)row*NN);
  float r[32];
  #pragma unroll
  for (int j=0;j<8;j++){
    float4 v = rp[j*64 + l];
    r[j*4+0]=v.x; r[j*4+1]=v.y; r[j*4+2]=v.z; r[j*4+3]=v.w;
  }
  // element r[u] has global index (u>>2)*256 + l*4 + (u&3); monotone in u per lane
  float bv = r[0]; int bi = 0;
  #pragma unroll
  for (int u=1;u<32;u++){ if (r[u] > bv){ bv = r[u]; bi = u; } }
  int myout = 0;
  for (int it=0; it<KK; ++it){
    int gidx = ((bi >> 2) << 8) | (l << 2) | (bi & 3);
    float v = bv; int gi = gidx;
    #pragma unroll
    for (int off=1; off<64; off<<=1){
      float ov = __shfl_xor(v, off);
      int og = __shfl_xor(gi, off);
      if (ov > v || (ov == v && og < gi)){ v = ov; gi = og; }
    }
    if (l == it) myout = gi;
    if (gi == gidx){            // this lane owned the winner: remove + rescan
      r[bi] = -3.4e38f;
      bv = r[0]; bi = 0;
      #pragma unroll
      for (int u=1;u<32;u++){ if (r[u] > bv){ bv = r[u]; bi = u; } }
    }
  }
  if (l < KK) idxo[row*KK + l] = myout;
}

// ---------- ctr part: c[p,o] = sum_{c<Ci} P[p,c] * W[o, c]  (first half of W) ----------
// grid: (BB*NN/16, Oi/64), block 256 = 16 tr x 16 tc, 4 cols/thread
__global__ __launch_bounds__(256) void k_ctr(const float* __restrict__ P, int stride, int Ci,
    const float* __restrict__ W, int twoCi, float* __restrict__ ctrb){
  __shared__ float Ps[16*132];
  int t = threadIdx.x, tr = t>>4, tc = t&15;
  int p0 = blockIdx.x*16, o0 = blockIdx.y*64;
  for (int e = t; e < 16*Ci; e += 256){
    int r = e / Ci, c = e - r*Ci;
    Ps[r*132 + c] = P[(size_t)(p0+r)*stride + c];
  }
  __syncthreads();
  float a0=0.f,a1=0.f,a2=0.f,a3=0.f;
  const float* w0 = W + (size_t)(o0 + tc*4)*twoCi;
  for (int c=0;c<Ci;c++){
    float pv = Ps[tr*132 + c];
    a0 += pv * w0[c];
    a1 += pv * w0[twoCi + c];
    a2 += pv * w0[2*twoCi + c];
    a3 += pv * w0[3*twoCi + c];
  }
  *(float4*)&ctrb[(size_t)(p0+tr)*256 + o0 + tc*4] = make_float4(a0,a1,a2,a3);
}

// ---------- fp32 diff-conv (layers 1-3): K = Ci only; epilogue adds ctr part ----------
// block: 4 points (80 rows) x 64 outputs. 256 thr = 16 tr (5 rows each) x 16 tc (4 o each)
__global__ __launch_bounds__(256) void k_conv(const float* __restrict__ P, int stride, int Ci,
    const float* __restrict__ W, int Oi, const int* __restrict__ idxg,
    const float* __restrict__ ctrb,
    float* __restrict__ ymax, float* __restrict__ ymin,
    float* __restrict__ chsum, float* __restrict__ chsq){
  __shared__ int lidx[80];
  __shared__ float ft[80*17];
  __shared__ float wt[16*68];
  __shared__ float red[16*16*4*4];
  int t = threadIdx.x;
  int blk = blockIdx.x;
  int b = blk / (NN/4);
  int n0 = (blk % (NN/4))*4;
  int o0 = blockIdx.y*64;
  if (t < 80) lidx[t] = idxg[((size_t)b*NN + n0 + t/20)*KK + (t%20)];
  int tr = t >> 4, tc = t & 15;
  int twoCi = 2*Ci;
  const float* Pb = P + (size_t)b*NN*stride;
  float acc[5][4];
  #pragma unroll
  for (int i=0;i<5;i++){ acc[i][0]=0.f; acc[i][1]=0.f; acc[i][2]=0.f; acc[i][3]=0.f; }
  int nchunks = (Ci + 15)/16;
  __syncthreads();
  for (int ch=0; ch<nchunks; ++ch){
    int c0 = ch*16;
    #pragma unroll
    for (int q=0;q<5;q++){
      int e = t + 256*q;
      int r = e >> 4, cc = e & 15;
      int c = c0 + cc;
      int n = n0 + r/20;
      float v = 0.f;
      if (c < Ci){
        int nbn = lidx[r];
        v = Pb[(size_t)nbn*stride + c] - Pb[(size_t)n*stride + c];
      }
      ft[r*17+cc] = v;
    }
    #pragma unroll
    for (int q=0;q<4;q++){
      int e = t + 256*q;
      int oi = e >> 4, cc = e & 15;
      int c = c0 + cc;
      wt[cc*68 + oi] = (c < Ci) ? W[(size_t)(o0+oi)*twoCi + Ci + c] : 0.f;
    }
    __syncthreads();
    #pragma unroll
    for (int j=0;j<16;j++){
      float4 wv = *reinterpret_cast<const float4*>(&wt[j*68 + tc*4]);
      #pragma unroll
      for (int i=0;i<5;i++){
        float a = ft[(tr*5+i)*17 + j];
        acc[i][0] += a*wv.x;
        acc[i][1] += a*wv.y;
        acc[i][2] += a*wv.z;
        acc[i][3] += a*wv.w;
      }
    }
    __syncthreads();
  }
  // stage 1: per-thread stats over its 5 rows (all same point); y = ctr + diff
  int nloc = tr >> 2;
  const float4 cv4 = *(const float4*)&ctrb[((size_t)b*NN + n0 + nloc)*256 + o0 + tc*4];
  const float* cvp = (const float*)&cv4;
  #pragma unroll
  for (int jj=0;jj<4;jj++){
    float cc = cvp[jj];
    float y0 = acc[0][jj] + cc;
    float mx = y0, mn = y0, s = y0, s2 = y0*y0;
    #pragma unroll
    for (int i=1;i<5;i++){
      float y = acc[i][jj] + cc;
      mx = fmaxf(mx,y); mn = fminf(mn,y); s += y; s2 += y*y;
    }
    float* rr = &red[((t*4)+jj)*4];
    rr[0]=mx; rr[1]=mn; rr[2]=s; rr[3]=s2;
  }
  __syncthreads();
  float ssave[4], s2save[4];
  bool isS2 = ((tr & 3) == 0);
  if (isS2){
    int n = n0 + (tr >> 2);
    float omax[4], omin[4];
    #pragma unroll
    for (int jj=0;jj<4;jj++){
      float mx=-3.4e38f, mn=3.4e38f, s=0.f, s2=0.f;
      #pragma unroll
      for (int u=0;u<4;u++){
        const float* rr = &red[((((tr+u)*16+tc)*4)+jj)*4];
        mx = fmaxf(mx, rr[0]); mn = fminf(mn, rr[1]); s += rr[2]; s2 += rr[3];
      }
      omax[jj]=mx; omin[jj]=mn; ssave[jj]=s; s2save[jj]=s2;
    }
    size_t base = ((size_t)b*NN + n)*256 + o0 + tc*4;
    *reinterpret_cast<float4*>(&ymax[base]) = make_float4(omax[0],omax[1],omax[2],omax[3]);
    *reinterpret_cast<float4*>(&ymin[base]) = make_float4(omin[0],omin[1],omin[2],omin[3]);
  }
  __syncthreads();
  if (isS2){
    float* rr  = &red[(((tr*16+tc)*4)+0)*4];
    rr[0]=ssave[0]; rr[1]=ssave[1]; rr[2]=ssave[2]; rr[3]=ssave[3];
    float* rr2 = &red[(((tr*16+tc)*4)+1)*4];
    rr2[0]=s2save[0]; rr2[1]=s2save[1]; rr2[2]=s2save[2]; rr2[3]=s2save[3];
  }
  __syncthreads();
  if (tr == 0){
    int slot = blk & (NSLOT-1);
    #pragma unroll
    for (int jj=0;jj<4;jj++){
      float s = 0.f, s2 = 0.f;
      #pragma unroll
      for (int u=0;u<16;u+=4){
        s  += red[(((u*16+tc)*4)+0)*4 + jj];
        s2 += red[(((u*16+tc)*4)+1)*4 + jj];
      }
      int o = o0 + tc*4 + jj;
      atomicAdd(&chsum[slot*256 + o], s);
      atomicAdd(&chsq[slot*256 + o], s2);
    }
  }
}

// ---------- MFMA diff-conv (layer 4): K = 128; epilogue adds fp32 ctr part ----------
__global__ __launch_bounds__(256) void k_convm(
    const __hip_bfloat16* __restrict__ PB, int stride,
    const __hip_bfloat16* __restrict__ Wd, int nchunk,
    const int* __restrict__ idxg, const float* __restrict__ ctrb,
    float* __restrict__ ymax, float* __restrict__ ymin,
    float* __restrict__ chsum, float* __restrict__ chsq)
{
  __shared__ __align__(16) char smem[40960];
  __hip_bfloat16* As = (__hip_bfloat16*)smem;       // [320][40]
  float* redmx = (float*)smem;                       // [80 gq][64 col]
  float* redmn = (float*)(smem + 20480);
  __shared__ int lidx[320];
  int t = threadIdx.x;
  int w = t >> 6, lane = t & 63, m = lane & 15, quad = lane >> 4;
  int p0 = blockIdx.x * 16;
  int b  = p0 >> 11;
  int o0 = blockIdx.y * 64;
  int Kpad = nchunk * 32;
  for (int q = t; q < 320; q += 256) lidx[q] = idxg[p0*KK + q];
  f32x4 acc[20];
  #pragma unroll
  for (int s=0;s<20;s++){ f32x4 z = {0.f,0.f,0.f,0.f}; acc[s] = z; }
  __syncthreads();

  const __hip_bfloat16* wrow = Wd + (size_t)(o0 + w*16 + m)*Kpad + quad*8;

  unsigned offn[5], offnb[5]; int lo[5];
  #pragma unroll
  for (int q=0;q<5;q++){
    int s = t + 256*q;
    int rr = s >> 2, seg = s & 3;
    int pp = (rr*6554) >> 17;                 // rr/20
    int n_g  = p0 + pp;
    int nb_g = (b<<11) + lidx[rr];
    offn[q]  = (unsigned)n_g*stride  + seg*8;
    offnb[q] = (unsigned)nb_g*stride + seg*8;
    lo[q] = rr*40 + seg*8;
  }
  for (int ch=0; ch<nchunk; ++ch){
    int c0 = ch*32;
    #pragma unroll
    for (int q=0;q<5;q++){
      s8v a  = *(const s8v*)&PB[offnb[q] + c0];
      s8v bb = *(const s8v*)&PB[offn[q]  + c0];
      *(s8v*)&As[lo[q]] = bsub8(a, bb);
    }
    __syncthreads();
    s8v bf = *(const s8v*)(wrow + c0);
    #pragma unroll
    for (int s=0;s<20;s++){
      s8v af = *(const s8v*)&As[(s*16+m)*40 + quad*8];
      acc[s] = __builtin_amdgcn_mfma_f32_16x16x32_bf16(af, bf, acc[s], 0, 0, 0);
    }
    __syncthreads();
  }

  int col = o0 + w*16 + m;
  float sm = 0.f, sq = 0.f;
  #pragma unroll
  for (int s=0;s<20;s++){
    int row0 = s*16 + quad*4;
    int pp = (row0*6554) >> 17;               // row0/20 (all 4 rows same point)
    float cc = ctrb[(size_t)(p0+pp)*256 + col];
    f32x4 a = acc[s];
    a.x += cc; a.y += cc; a.z += cc; a.w += cc;
    float mx = fmaxf(fmaxf(a.x,a.y), fmaxf(a.z,a.w));
    float mn = fminf(fminf(a.x,a.y), fminf(a.z,a.w));
    sm += a.x + a.y + a.z + a.w;
    sq += a.x*a.x + a.y*a.y + a.z*a.z + a.w*a.w;
    int gq = s*4 + quad;
    redmx[gq*64 + w*16 + m] = mx;
    redmn[gq*64 + w*16 + m] = mn;
  }
  sm += __shfl_xor(sm, 16); sq += __shfl_xor(sq, 16);
  sm += __shfl_xor(sm, 32); sq += __shfl_xor(sq, 32);
  if (quad == 0){
    int slot = blockIdx.x & (NSLOT-1);
    atomicAdd(&chsum[slot*256 + col], sm);
    atomicAdd(&chsq [slot*256 + col], sq);
  }
  __syncthreads();
  #pragma unroll
  for (int q=0;q<4;q++){
    int i = t + 256*q;
    int pp = i >> 6, c2 = i & 63;
    float mx = redmx[(pp*5)*64 + c2];
    float mn = redmn[(pp*5)*64 + c2];
    #pragma unroll
    for (int u=1;u<5;u++){
      mx = fmaxf(mx, redmx[(pp*5+u)*64 + c2]);
      mn = fminf(mn, redmn[(pp*5+u)*64 + c2]);
    }
    size_t base = ((size_t)(p0+pp))*256 + o0 + c2;
    ymax[base] = mx;
    ymin[base] = mn;
  }
}

// ---------- BN stats finalize ----------
__global__ __launch_bounds__(256) void k_bnstats(const float* __restrict__ chsum, const float* __restrict__ chsq,
    const float* __restrict__ g, const float* __restrict__ bet,
    float* __restrict__ scl, float* __restrict__ shf, int Oi){
  int o = threadIdx.x;
  if (o >= Oi) return;
  float s=0.f, s2=0.f;
  for (int u=0;u<NSLOT;u++){ s += chsum[u*256+o]; s2 += chsq[u*256+o]; }
  float cnt = (float)(BB*NN*KK);
  float mean = s/cnt;
  float var = s2/cnt - mean*mean;
  float sc = g[o] / sqrtf(var + LEPS);
  scl[o] = sc;
  shf[o] = bet[o] - mean*sc;
}

// ---------- apply BN+LReLU, write fp32 xc + bf16 xcb ----------
__global__ __launch_bounds__(256) void k_apply(const float* __restrict__ ymax, const float* __restrict__ ymin,
    const float* __restrict__ scl, const float* __restrict__ shf,
    float* __restrict__ xc, __hip_bfloat16* __restrict__ xcb, int off, int Oi){
  int i = blockIdx.x*256 + threadIdx.x;
  if (i >= BB*NN*Oi) return;
  int o = i & (Oi-1);
  size_t p = (size_t)((unsigned)i / (unsigned)Oi);
  float sc = scl[o];
  float v = (sc >= 0.f) ? ymax[p*256+o] : ymin[p*256+o];
  float r = lrelu(v*sc + shf[o]);
  xc [p*XCCH + off + o] = r;
  xcb[p*XCCH + off + o] = __float2bfloat16(r);
}

// ---------- MFMA conv5 ----------
__global__ __launch_bounds__(256) void k_conv5m(const __hip_bfloat16* __restrict__ xcb,
    const __hip_bfloat16* __restrict__ w5b,
    float* __restrict__ pmax, float* __restrict__ pmin,
    float* __restrict__ psum, float* __restrict__ psq)
{
  int t = threadIdx.x, w = t >> 6, lane = t & 63, m = lane & 15, quad = lane >> 4;
  int nbk = blockIdx.x, b = blockIdx.z;
  int o0 = blockIdx.y * 64;
  int n0 = nbk * 256;
  const __hip_bfloat16* arow = xcb + (size_t)(b*NN + n0 + m)*XCCH + quad*8;
  const __hip_bfloat16* brow = w5b + (size_t)(o0 + w*16 + m)*XCCH + quad*8;
  f32x4 acc[16];
  #pragma unroll
  for (int s=0;s<16;s++){ f32x4 z = {0.f,0.f,0.f,0.f}; acc[s] = z; }
  for (int ch=0; ch<16; ++ch){
    int c0 = ch*32;
    s8v bf = *(const s8v*)(brow + c0);
    #pragma unroll
    for (int s=0;s<16;s++){
      s8v af = *(const s8v*)(arow + (size_t)s*16*XCCH + c0);
      acc[s] = __builtin_amdgcn_mfma_f32_16x16x32_bf16(af, bf, acc[s], 0, 0, 0);
    }
  }
  float mx = -3.4e38f, mn = 3.4e38f, sm = 0.f, sq = 0.f;
  #pragma unroll
  for (int s=0;s<16;s++){
    f32x4 a = acc[s];
    mx = fmaxf(mx, fmaxf(fmaxf(a.x,a.y), fmaxf(a.z,a.w)));
    mn = fminf(mn, fminf(fminf(a.x,a.y), fminf(a.z,a.w)));
    sm += a.x + a.y + a.z + a.w;
    sq += a.x*a.x + a.y*a.y + a.z*a.z + a.w*a.w;
  }
  #pragma unroll
  for (int off=16; off<=32; off<<=1){
    mx = fmaxf(mx, __shfl_xor(mx, off));
    mn = fminf(mn, __shfl_xor(mn, off));
    sm += __shfl_xor(sm, off);
    sq += __shfl_xor(sq, off);
  }
  if (quad == 0){
    size_t ii = ((size_t)b*1024 + o0 + w*16 + m)*8 + nbk;
    pmax[ii] = mx; pmin[ii] = mn; psum[ii] = sm; psq[ii] = sq;
  }
}

__global__ __launch_bounds__(256) void k_stats5(const float* __restrict__ psum, const float* __restrict__ psq,
    const float* __restrict__ g5, const float* __restrict__ b5,
    float* __restrict__ sc5, float* __restrict__ sh5){
  int o = blockIdx.x*256 + threadIdx.x;
  float s=0.f, s2=0.f;
  for (int b=0;b<BB;b++){
    const float* ps = &psum[((size_t)b*1024 + o)*8];
    const float* pq = &psq [((size_t)b*1024 + o)*8];
    #pragma unroll
    for (int u=0;u<8;u++){ s += ps[u]; s2 += pq[u]; }
  }
  float cnt = (float)(BB*NN);
  float mean = s/cnt;
  float var = s2/cnt - mean*mean;
  float sc = g5[o] / sqrtf(var + LEPS);
  sc5[o] = sc;
  sh5[o] = b5[o] - mean*sc;
}

__global__ __launch_bounds__(256) void k_apply5(const float* __restrict__ pmax, const float* __restrict__ pmin,
    const float* __restrict__ sc5, const float* __restrict__ sh5, float* __restrict__ out){
  int i = blockIdx.x*256 + threadIdx.x;
  int o = i & 1023;
  float sc = sc5[o];
  float v;
  if (sc >= 0.f){
    const float* p = &pmax[(size_t)i*8];
    v = p[0];
    #pragma unroll
    for (int u=1;u<8;u++) v = fmaxf(v, p[u]);
  } else {
    const float* p = &pmin[(size_t)i*8];
    v = p[0];
    #pragma unroll
    for (int u=1;u<8;u++) v = fminf(v, p[u]);
  }
  out[i] = lrelu(v*sc + sh5[o]);
}

extern "C" void kernel_launch(void* const* d_in, const int* in_sizes, int n_in,
                              void* d_out, int out_size, void* d_ws, size_t ws_size,
                              hipStream_t stream){
  const float* x  = (const float*)d_in[0];
  const float* w1 = (const float*)d_in[1];
  const float* g1 = (const float*)d_in[2];
  const float* b1 = (const float*)d_in[3];
  const float* w2 = (const float*)d_in[4];
  const float* g2 = (const float*)d_in[5];
  const float* b2 = (const float*)d_in[6];
  const float* w3 = (const float*)d_in[7];
  const float* g3 = (const float*)d_in[8];
  const float* b3 = (const float*)d_in[9];
  const float* w4 = (const float*)d_in[10];
  const float* g4 = (const float*)d_in[11];
  const float* b4 = (const float*)d_in[12];
  const float* w5 = (const float*)d_in[13];
  const float* g5 = (const float*)d_in[14];
  const float* b5 = (const float*)d_in[15];
  float* out = (float*)d_out;
  float* ws = (float*)d_ws;

  const size_t F_PD   = 0;
  const size_t F_XT0  = F_PD   + (size_t)BB*NN*NN;
  const size_t F_XC   = F_XT0  + (size_t)BB*NN*4;
  const size_t F_CHS  = F_XC   + (size_t)BB*NN*XCCH;
  const size_t F_CHQ  = F_CHS  + (size_t)NSLOT*256;
  const size_t F_SCL  = F_CHQ  + (size_t)NSLOT*256;
  const size_t F_SHF  = F_SCL  + 256;
  const size_t F_SQ   = F_SHF  + 256;
  const size_t F_IDX  = F_SQ   + (size_t)BB*NN;
  const size_t F_PMAX = F_IDX  + (size_t)BB*NN*KK;
  const size_t F_PMIN = F_PMAX + (size_t)BB*1024*8;
  const size_t F_PSUM = F_PMIN + (size_t)BB*1024*8;
  const size_t F_PSQ  = F_PSUM + (size_t)BB*1024*8;
  const size_t F_SC5  = F_PSQ  + (size_t)BB*1024*8;
  const size_t F_SH5  = F_SC5  + 1024;
  const size_t F_XCB  = F_SH5  + 1024;
  const size_t F_WB   = F_XCB  + (size_t)BB*NN*XCCH/2;

  float* pd    = ws + F_PD;
  float* ctrb  = pd;                          // [B*N,256] fp32, alias pd[0..4.2M) (pd dead after k_topk)
  float* ymax  = pd + (size_t)16*1024*1024;   // alias pd upper
  float* ymin  = pd + (size_t)21*1024*1024;
  float* xt0   = ws + F_XT0;
  float* xc    = ws + F_XC;
  float* chsum = ws + F_CHS;
  float* chsq  = ws + F_CHQ;
  float* scl   = ws + F_SCL;
  float* shf   = ws + F_SHF;
  float* sqb   = ws + F_SQ;
  int*   idxb  = (int*)(ws + F_IDX);
  float* pmax  = ws + F_PMAX;
  float* pmin  = ws + F_PMIN;
  float* psum  = ws + F_PSUM;
  float* psq   = ws + F_PSQ;
  float* sc5   = ws + F_SC5;
  float* sh5   = ws + F_SH5;
  __hip_bfloat16* xcb = (__hip_bfloat16*)(ws + F_XCB);
  __hip_bfloat16* wb  = (__hip_bfloat16*)(ws + F_WB);
  __hip_bfloat16* w4d = wb;            // 256x128 (diff half of w4)
  __hip_bfloat16* w5b = wb + 32768;    // 1024x512

  (void)in_sizes; (void)n_in; (void)out_size; (void)ws_size;

  k_transpose<<<64, 256, 0, stream>>>(x, xt0);
  k_cvtw<<<(32768+255)/256,  256, 0, stream>>>(w4, w4d, 256, 128, 128, 128, 32768);
  k_cvtw<<<(524288+255)/256, 256, 0, stream>>>(w5, w5b, 512, 0, 512, 512, 524288);

  struct LayerP { const float* P; int stride; int Ci; int CiD; const float* W; const float* g; const float* b; int Oi; int off; };
  LayerP L[4] = {
    { xt0,    4,   3,   4,   w1, g1, b1,  64, 0   },
    { xc,     512, 64,  64,  w2, g2, b2,  64, 64  },
    { xc+64,  512, 64,  64,  w3, g3, b3, 128, 128 },
    { xc+128, 512, 128, 128, w4, g4, b4, 256, 256 },
  };

  for (int l=0; l<4; ++l){
    k_sq<<<64, 256, 0, stream>>>(L[l].P, L[l].stride, L[l].CiD, sqb);
    k_dist<<<dim3(16,16,8), 256, 0, stream>>>(L[l].P, L[l].stride, L[l].CiD, sqb, pd);
    k_topk<<<BB*NN/4, 256, 0, stream>>>(pd, idxb);
    hipMemsetAsync(chsum, 0, (size_t)NSLOT*256*2*sizeof(float), stream);
    k_ctr<<<dim3(BB*NN/16, L[l].Oi/64), 256, 0, stream>>>(L[l].P, L[l].stride, L[l].Ci, L[l].W, 2*L[l].Ci, ctrb);
    if (l < 3){
      k_conv<<<dim3(BB*NN/4, L[l].Oi/64), 256, 0, stream>>>(L[l].P, L[l].stride, L[l].Ci, L[l].W, L[l].Oi,
                                                            idxb, ctrb, ymax, ymin, chsum, chsq);
    } else {
      k_convm<<<dim3(BB*NN/16, 4), 256, 0, stream>>>(xcb+128, XCCH, w4d, 4,
                                                     idxb, ctrb, ymax, ymin, chsum, chsq);
    }
    k_bnstats<<<1, 256, 0, stream>>>(chsum, chsq, L[l].g, L[l].b, scl, shf, L[l].Oi);
    k_apply<<<(BB*NN*L[l].Oi + 255)/256, 256, 0, stream>>>(ymax, ymin, scl, shf, xc, xcb, L[l].off, L[l].Oi);
  }

  k_conv5m<<<dim3(8, 16, BB), 256, 0, stream>>>(xcb, w5b, pmax, pmin, psum, psq);
  k_stats5<<<4, 256, 0, stream>>>(psum, psq, g5, b5, sc5, sh5);
  k_apply5<<<(BB*1024)/256, 256, 0, stream>>>(pmax, pmin, sc5, sh5, out);
}

// Round 5
// 1579.089 us; speedup vs baseline: 2.1051x; 1.1745x over previous
//
#include <hip/hip_runtime.h>
#include <hip/hip_bf16.h>
#include <math.h>

#define BB 8
#define NN 2048
#define KK 20
#define XCCH 512
#define NSLOT 64
#define LEPS 1e-5f

typedef __attribute__((ext_vector_type(8))) short s8v;
typedef __attribute__((ext_vector_type(4))) float f32x4;

__device__ __forceinline__ float lrelu(float x){ return x >= 0.f ? x : 0.2f*x; }

__device__ __forceinline__ s8v bsub8(s8v a, s8v b){
  union U { s8v s; __hip_bfloat162 h[4]; } A, B, R;
  A.s = a; B.s = b;
  #pragma unroll
  for (int i=0;i<4;i++) R.h[i] = __hsub2(A.h[i], B.h[i]);
  return R.s;
}

// ---------- transpose x (B,3,N) -> xt0 (B*N,4) fp32 ----------
__global__ __launch_bounds__(256) void k_transpose(const float* __restrict__ x, float* __restrict__ xt){
  int i = blockIdx.x*256 + threadIdx.x;
  if (i >= BB*NN) return;
  int b = i >> 11, n = i & (NN-1);
  float4 v;
  v.x = x[(b*3+0)*NN + n];
  v.y = x[(b*3+1)*NN + n];
  v.z = x[(b*3+2)*NN + n];
  v.w = 0.f;
  reinterpret_cast<float4*>(xt)[i] = v;
}

// ---------- weight fp32 -> bf16 slice with K padding ----------
__global__ __launch_bounds__(256) void k_cvtw(const float* __restrict__ W, __hip_bfloat16* __restrict__ Wb,
                                              int Cs, int coff, int Ccnt, int Cpad, int total){
  int i = blockIdx.x*256 + threadIdx.x;
  if (i >= total) return;
  int o = i / Cpad, c = i - o*Cpad;
  Wb[i] = (c < Ccnt) ? __float2bfloat16(W[(size_t)o*Cs + coff + c]) : __float2bfloat16(0.f);
}

// ---------- squared norms ----------
__global__ __launch_bounds__(256) void k_sq(const float* __restrict__ P, int stride, int Ci, float* __restrict__ sq){
  int i = blockIdx.x*256 + threadIdx.x;
  if (i >= BB*NN) return;
  const float* p = P + (size_t)i*stride;
  float s = 0.f;
  for (int c = 0; c < Ci; ++c){ float v = p[c]; s += v*v; }
  sq[i] = s;
}

// ---------- pairwise score pd = 2*dot - sq_n - sq_m (fp32) ----------
__global__ __launch_bounds__(256) void k_dist(const float* __restrict__ P, int stride, int Ci,
                                              const float* __restrict__ sq, float* __restrict__ pd){
  __shared__ float At[128*17];
  __shared__ float Bt[128*17];
  int b = blockIdx.z;
  int n0 = blockIdx.y*128, m0 = blockIdx.x*128;
  int t = threadIdx.x;
  int ty = t >> 4, tx = t & 15;
  float acc[8][8];
  #pragma unroll
  for (int i=0;i<8;i++)
    #pragma unroll
    for (int j=0;j<8;j++) acc[i][j]=0.f;
  const float* Pb = P + (size_t)b*NN*stride;
  for (int c0 = 0; c0 < Ci; c0 += 16){
    #pragma unroll
    for (int q = 0; q < 8; ++q){
      int e = t + 256*q;
      int r = e >> 4, cc = e & 15;
      int c = c0 + cc;
      bool ok = (c < Ci);
      At[r*17+cc] = ok ? Pb[(size_t)(n0+r)*stride + c] : 0.f;
      Bt[r*17+cc] = ok ? Pb[(size_t)(m0+r)*stride + c] : 0.f;
    }
    __syncthreads();
    #pragma unroll
    for (int j = 0; j < 16; ++j){
      float a[8], bv[8];
      #pragma unroll
      for (int i=0;i<8;i++) a[i]  = At[(ty*8+i)*17 + j];
      #pragma unroll
      for (int i=0;i<8;i++) bv[i] = Bt[(tx*8+i)*17 + j];
      #pragma unroll
      for (int i=0;i<8;i++)
        #pragma unroll
        for (int jj=0;jj<8;jj++) acc[i][jj] += a[i]*bv[jj];
    }
    __syncthreads();
  }
  float sqn[8], sqm[8];
  #pragma unroll
  for (int i=0;i<8;i++) sqn[i] = sq[b*NN + n0 + ty*8 + i];
  #pragma unroll
  for (int i=0;i<8;i++) sqm[i] = sq[b*NN + m0 + tx*8 + i];
  #pragma unroll
  for (int i=0;i<8;i++){
    size_t base = ((size_t)b*NN + n0+ty*8+i)*NN + m0 + tx*8;
    float4 v0, v1;
    v0.x = 2.f*acc[i][0] - sqn[i] - sqm[0];
    v0.y = 2.f*acc[i][1] - sqn[i] - sqm[1];
    v0.z = 2.f*acc[i][2] - sqn[i] - sqm[2];
    v0.w = 2.f*acc[i][3] - sqn[i] - sqm[3];
    v1.x = 2.f*acc[i][4] - sqn[i] - sqm[4];
    v1.y = 2.f*acc[i][5] - sqn[i] - sqm[5];
    v1.z = 2.f*acc[i][6] - sqn[i] - sqm[6];
    v1.w = 2.f*acc[i][7] - sqn[i] - sqm[7];
    reinterpret_cast<float4*>(pd + base)[0] = v0;
    reinterpret_cast<float4*>(pd + base)[1] = v1;
  }
}

// ---------- top-20 per row: one wave per row, no barriers ----------
__global__ __launch_bounds__(256) void k_topk(const float* __restrict__ pd, int* __restrict__ idxo){
  int t = threadIdx.x;
  int l = t & 63;
  int row = blockIdx.x*4 + (t >> 6);
  const float4* rp = (const float4*)(pd + (size_t)row*NN);
  float r[32];
  #pragma unroll
  for (int j=0;j<8;j++){
    float4 v = rp[j*64 + l];
    r[j*4+0]=v.x; r[j*4+1]=v.y; r[j*4+2]=v.z; r[j*4+3]=v.w;
  }
  float bv = r[0]; int bi = 0;
  #pragma unroll
  for (int u=1;u<32;u++){ if (r[u] > bv){ bv = r[u]; bi = u; } }
  int myout = 0;
  for (int it=0; it<KK; ++it){
    int gidx = ((bi >> 2) << 8) | (l << 2) | (bi & 3);
    float v = bv; int gi = gidx;
    #pragma unroll
    for (int off=1; off<64; off<<=1){
      float ov = __shfl_xor(v, off);
      int og = __shfl_xor(gi, off);
      if (ov > v || (ov == v && og < gi)){ v = ov; gi = og; }
    }
    if (l == it) myout = gi;
    if (gi == gidx){
      r[bi] = -3.4e38f;
      bv = r[0]; bi = 0;
      #pragma unroll
      for (int u=1;u<32;u++){ if (r[u] > bv){ bv = r[u]; bi = u; } }
    }
  }
  if (l < KK) idxo[row*KK + l] = myout;
}

// ---------- ctr part: register-tiled GEMM, 64 pts x 64 outs per block ----------
// ctrb[p,o] = sum_{c<Ci} P[p,c] * W[o,c]   (first half of W rows)
__global__ __launch_bounds__(256) void k_ctr(const float* __restrict__ P, int stride, int Ci,
    const float* __restrict__ W, int twoCi, float* __restrict__ ctrb){
  __shared__ float Pt[64*17];
  __shared__ float Wt[64*17];
  int t = threadIdx.x, ty = t >> 4, tx = t & 15;
  int p0 = blockIdx.x*64, o0 = blockIdx.y*64;
  float acc[4][4];
  #pragma unroll
  for (int i=0;i<4;i++)
    #pragma unroll
    for (int j=0;j<4;j++) acc[i][j]=0.f;
  for (int c0 = 0; c0 < Ci; c0 += 16){
    #pragma unroll
    for (int q=0;q<4;q++){
      int e = t + 256*q;           // 0..1023 = 64 rows x 16 cols
      int r = e >> 4, cc = e & 15;
      int c = c0 + cc;
      bool ok = (c < Ci);
      Pt[r*17+cc] = ok ? P[(size_t)(p0+r)*stride + c] : 0.f;
      Wt[r*17+cc] = ok ? W[(size_t)(o0+r)*twoCi + c] : 0.f;
    }
    __syncthreads();
    #pragma unroll
    for (int j=0;j<16;j++){
      float a[4], bv[4];
      #pragma unroll
      for (int i=0;i<4;i++) a[i]  = Pt[(ty*4+i)*17 + j];
      #pragma unroll
      for (int i=0;i<4;i++) bv[i] = Wt[(tx*4+i)*17 + j];
      #pragma unroll
      for (int i=0;i<4;i++)
        #pragma unroll
        for (int jj=0;jj<4;jj++) acc[i][jj] += a[i]*bv[jj];
    }
    __syncthreads();
  }
  #pragma unroll
  for (int i=0;i<4;i++){
    *(float4*)&ctrb[(size_t)(p0+ty*4+i)*256 + o0 + tx*4] =
      make_float4(acc[i][0], acc[i][1], acc[i][2], acc[i][3]);
  }
}

// ---------- fp32 diff-conv (layers 1-3): K = Ci only; epilogue adds ctr part ----------
__global__ __launch_bounds__(256) void k_conv(const float* __restrict__ P, int stride, int Ci,
    const float* __restrict__ W, int Oi, const int* __restrict__ idxg,
    const float* __restrict__ ctrb,
    float* __restrict__ ymax, float* __restrict__ ymin,
    float* __restrict__ chsum, float* __restrict__ chsq){
  __shared__ int lidx[80];
  __shared__ float ft[80*17];
  __shared__ float wt[16*68];
  __shared__ float red[16*16*4*4];
  int t = threadIdx.x;
  int blk = blockIdx.x;
  int b = blk / (NN/4);
  int n0 = (blk % (NN/4))*4;
  int o0 = blockIdx.y*64;
  if (t < 80) lidx[t] = idxg[((size_t)b*NN + n0 + t/20)*KK + (t%20)];
  int tr = t >> 4, tc = t & 15;
  int twoCi = 2*Ci;
  const float* Pb = P + (size_t)b*NN*stride;
  float acc[5][4];
  #pragma unroll
  for (int i=0;i<5;i++){ acc[i][0]=0.f; acc[i][1]=0.f; acc[i][2]=0.f; acc[i][3]=0.f; }
  int nchunks = (Ci + 15)/16;
  __syncthreads();
  for (int ch=0; ch<nchunks; ++ch){
    int c0 = ch*16;
    #pragma unroll
    for (int q=0;q<5;q++){
      int e = t + 256*q;
      int r = e >> 4, cc = e & 15;
      int c = c0 + cc;
      int n = n0 + r/20;
      float v = 0.f;
      if (c < Ci){
        int nbn = lidx[r];
        v = Pb[(size_t)nbn*stride + c] - Pb[(size_t)n*stride + c];
      }
      ft[r*17+cc] = v;
    }
    #pragma unroll
    for (int q=0;q<4;q++){
      int e = t + 256*q;
      int oi = e >> 4, cc = e & 15;
      int c = c0 + cc;
      wt[cc*68 + oi] = (c < Ci) ? W[(size_t)(o0+oi)*twoCi + Ci + c] : 0.f;
    }
    __syncthreads();
    #pragma unroll
    for (int j=0;j<16;j++){
      float4 wv = *reinterpret_cast<const float4*>(&wt[j*68 + tc*4]);
      #pragma unroll
      for (int i=0;i<5;i++){
        float a = ft[(tr*5+i)*17 + j];
        acc[i][0] += a*wv.x;
        acc[i][1] += a*wv.y;
        acc[i][2] += a*wv.z;
        acc[i][3] += a*wv.w;
      }
    }
    __syncthreads();
  }
  int nloc = tr >> 2;
  const float4 cv4 = *(const float4*)&ctrb[((size_t)b*NN + n0 + nloc)*256 + o0 + tc*4];
  const float* cvp = (const float*)&cv4;
  #pragma unroll
  for (int jj=0;jj<4;jj++){
    float cc = cvp[jj];
    float y0 = acc[0][jj] + cc;
    float mx = y0, mn = y0, s = y0, s2 = y0*y0;
    #pragma unroll
    for (int i=1;i<5;i++){
      float y = acc[i][jj] + cc;
      mx = fmaxf(mx,y); mn = fminf(mn,y); s += y; s2 += y*y;
    }
    float* rr = &red[((t*4)+jj)*4];
    rr[0]=mx; rr[1]=mn; rr[2]=s; rr[3]=s2;
  }
  __syncthreads();
  float ssave[4], s2save[4];
  bool isS2 = ((tr & 3) == 0);
  if (isS2){
    int n = n0 + (tr >> 2);
    float omax[4], omin[4];
    #pragma unroll
    for (int jj=0;jj<4;jj++){
      float mx=-3.4e38f, mn=3.4e38f, s=0.f, s2=0.f;
      #pragma unroll
      for (int u=0;u<4;u++){
        const float* rr = &red[((((tr+u)*16+tc)*4)+jj)*4];
        mx = fmaxf(mx, rr[0]); mn = fminf(mn, rr[1]); s += rr[2]; s2 += rr[3];
      }
      omax[jj]=mx; omin[jj]=mn; ssave[jj]=s; s2save[jj]=s2;
    }
    size_t base = ((size_t)b*NN + n)*256 + o0 + tc*4;
    *reinterpret_cast<float4*>(&ymax[base]) = make_float4(omax[0],omax[1],omax[2],omax[3]);
    *reinterpret_cast<float4*>(&ymin[base]) = make_float4(omin[0],omin[1],omin[2],omin[3]);
  }
  __syncthreads();
  if (isS2){
    float* rr  = &red[(((tr*16+tc)*4)+0)*4];
    rr[0]=ssave[0]; rr[1]=ssave[1]; rr[2]=ssave[2]; rr[3]=ssave[3];
    float* rr2 = &red[(((tr*16+tc)*4)+1)*4];
    rr2[0]=s2save[0]; rr2[1]=s2save[1]; rr2[2]=s2save[2]; rr2[3]=s2save[3];
  }
  __syncthreads();
  if (tr == 0){
    int slot = blk & (NSLOT-1);
    #pragma unroll
    for (int jj=0;jj<4;jj++){
      float s = 0.f, s2 = 0.f;
      #pragma unroll
      for (int u=0;u<16;u+=4){
        s  += red[(((u*16+tc)*4)+0)*4 + jj];
        s2 += red[(((u*16+tc)*4)+1)*4 + jj];
      }
      int o = o0 + tc*4 + jj;
      atomicAdd(&chsum[slot*256 + o], s);
      atomicAdd(&chsq[slot*256 + o], s2);
    }
  }
}

// ---------- MFMA diff-conv (layer 4): K = 128; epilogue adds fp32 ctr part ----------
__global__ __launch_bounds__(256) void k_convm(
    const __hip_bfloat16* __restrict__ PB, int stride,
    const __hip_bfloat16* __restrict__ Wd, int nchunk,
    const int* __restrict__ idxg, const float* __restrict__ ctrb,
    float* __restrict__ ymax, float* __restrict__ ymin,
    float* __restrict__ chsum, float* __restrict__ chsq)
{
  __shared__ __align__(16) char smem[40960];
  __hip_bfloat16* As = (__hip_bfloat16*)smem;
  float* redmx = (float*)smem;
  float* redmn = (float*)(smem + 20480);
  __shared__ int lidx[320];
  int t = threadIdx.x;
  int w = t >> 6, lane = t & 63, m = lane & 15, quad = lane >> 4;
  int p0 = blockIdx.x * 16;
  int b  = p0 >> 11;
  int o0 = blockIdx.y * 64;
  int Kpad = nchunk * 32;
  for (int q = t; q < 320; q += 256) lidx[q] = idxg[p0*KK + q];
  f32x4 acc[20];
  #pragma unroll
  for (int s=0;s<20;s++){ f32x4 z = {0.f,0.f,0.f,0.f}; acc[s] = z; }
  __syncthreads();

  const __hip_bfloat16* wrow = Wd + (size_t)(o0 + w*16 + m)*Kpad + quad*8;

  unsigned offn[5], offnb[5]; int lo[5];
  #pragma unroll
  for (int q=0;q<5;q++){
    int s = t + 256*q;
    int rr = s >> 2, seg = s & 3;
    int pp = (rr*6554) >> 17;
    int n_g  = p0 + pp;
    int nb_g = (b<<11) + lidx[rr];
    offn[q]  = (unsigned)n_g*stride  + seg*8;
    offnb[q] = (unsigned)nb_g*stride + seg*8;
    lo[q] = rr*40 + seg*8;
  }
  for (int ch=0; ch<nchunk; ++ch){
    int c0 = ch*32;
    #pragma unroll
    for (int q=0;q<5;q++){
      s8v a  = *(const s8v*)&PB[offnb[q] + c0];
      s8v bb = *(const s8v*)&PB[offn[q]  + c0];
      *(s8v*)&As[lo[q]] = bsub8(a, bb);
    }
    __syncthreads();
    s8v bf = *(const s8v*)(wrow + c0);
    #pragma unroll
    for (int s=0;s<20;s++){
      s8v af = *(const s8v*)&As[(s*16+m)*40 + quad*8];
      acc[s] = __builtin_amdgcn_mfma_f32_16x16x32_bf16(af, bf, acc[s], 0, 0, 0);
    }
    __syncthreads();
  }

  int col = o0 + w*16 + m;
  float sm = 0.f, sq = 0.f;
  #pragma unroll
  for (int s=0;s<20;s++){
    int row0 = s*16 + quad*4;
    int pp = (row0*6554) >> 17;
    float cc = ctrb[(size_t)(p0+pp)*256 + col];
    f32x4 a = acc[s];
    a.x += cc; a.y += cc; a.z += cc; a.w += cc;
    float mx = fmaxf(fmaxf(a.x,a.y), fmaxf(a.z,a.w));
    float mn = fminf(fminf(a.x,a.y), fminf(a.z,a.w));
    sm += a.x + a.y + a.z + a.w;
    sq += a.x*a.x + a.y*a.y + a.z*a.z + a.w*a.w;
    int gq = s*4 + quad;
    redmx[gq*64 + w*16 + m] = mx;
    redmn[gq*64 + w*16 + m] = mn;
  }
  sm += __shfl_xor(sm, 16); sq += __shfl_xor(sq, 16);
  sm += __shfl_xor(sm, 32); sq += __shfl_xor(sq, 32);
  if (quad == 0){
    int slot = blockIdx.x & (NSLOT-1);
    atomicAdd(&chsum[slot*256 + col], sm);
    atomicAdd(&chsq [slot*256 + col], sq);
  }
  __syncthreads();
  #pragma unroll
  for (int q=0;q<4;q++){
    int i = t + 256*q;
    int pp = i >> 6, c2 = i & 63;
    float mx = redmx[(pp*5)*64 + c2];
    float mn = redmn[(pp*5)*64 + c2];
    #pragma unroll
    for (int u=1;u<5;u++){
      mx = fmaxf(mx, redmx[(pp*5+u)*64 + c2]);
      mn = fminf(mn, redmn[(pp*5+u)*64 + c2]);
    }
    size_t base = ((size_t)(p0+pp))*256 + o0 + c2;
    ymax[base] = mx;
    ymin[base] = mn;
  }
}

// ---------- BN stats finalize ----------
__global__ __launch_bounds__(256) void k_bnstats(const float* __restrict__ chsum, const float* __restrict__ chsq,
    const float* __restrict__ g, const float* __restrict__ bet,
    float* __restrict__ scl, float* __restrict__ shf, int Oi){
  int o = threadIdx.x;
  if (o >= Oi) return;
  float s=0.f, s2=0.f;
  for (int u=0;u<NSLOT;u++){ s += chsum[u*256+o]; s2 += chsq[u*256+o]; }
  float cnt = (float)(BB*NN*KK);
  float mean = s/cnt;
  float var = s2/cnt - mean*mean;
  float sc = g[o] / sqrtf(var + LEPS);
  scl[o] = sc;
  shf[o] = bet[o] - mean*sc;
}

// ---------- apply BN+LReLU, write fp32 xc + bf16 xcb ----------
__global__ __launch_bounds__(256) void k_apply(const float* __restrict__ ymax, const float* __restrict__ ymin,
    const float* __restrict__ scl, const float* __restrict__ shf,
    float* __restrict__ xc, __hip_bfloat16* __restrict__ xcb, int off, int Oi){
  int i = blockIdx.x*256 + threadIdx.x;
  if (i >= BB*NN*Oi) return;
  int o = i & (Oi-1);
  size_t p = (size_t)((unsigned)i / (unsigned)Oi);
  float sc = scl[o];
  float v = (sc >= 0.f) ? ymax[p*256+o] : ymin[p*256+o];
  float r = lrelu(v*sc + shf[o]);
  xc [p*XCCH + off + o] = r;
  xcb[p*XCCH + off + o] = __float2bfloat16(r);
}

// ---------- MFMA conv5 ----------
__global__ __launch_bounds__(256) void k_conv5m(const __hip_bfloat16* __restrict__ xcb,
    const __hip_bfloat16* __restrict__ w5b,
    float* __restrict__ pmax, float* __restrict__ pmin,
    float* __restrict__ psum, float* __restrict__ psq)
{
  int t = threadIdx.x, w = t >> 6, lane = t & 63, m = lane & 15, quad = lane >> 4;
  int nbk = blockIdx.x, b = blockIdx.z;
  int o0 = blockIdx.y * 64;
  int n0 = nbk * 256;
  const __hip_bfloat16* arow = xcb + (size_t)(b*NN + n0 + m)*XCCH + quad*8;
  const __hip_bfloat16* brow = w5b + (size_t)(o0 + w*16 + m)*XCCH + quad*8;
  f32x4 acc[16];
  #pragma unroll
  for (int s=0;s<16;s++){ f32x4 z = {0.f,0.f,0.f,0.f}; acc[s] = z; }
  for (int ch=0; ch<16; ++ch){
    int c0 = ch*32;
    s8v bf = *(const s8v*)(brow + c0);
    #pragma unroll
    for (int s=0;s<16;s++){
      s8v af = *(const s8v*)(arow + (size_t)s*16*XCCH + c0);
      acc[s] = __builtin_amdgcn_mfma_f32_16x16x32_bf16(af, bf, acc[s], 0, 0, 0);
    }
  }
  float mx = -3.4e38f, mn = 3.4e38f, sm = 0.f, sq = 0.f;
  #pragma unroll
  for (int s=0;s<16;s++){
    f32x4 a = acc[s];
    mx = fmaxf(mx, fmaxf(fmaxf(a.x,a.y), fmaxf(a.z,a.w)));
    mn = fminf(mn, fminf(fminf(a.x,a.y), fminf(a.z,a.w)));
    sm += a.x + a.y + a.z + a.w;
    sq += a.x*a.x + a.y*a.y + a.z*a.z + a.w*a.w;
  }
  #pragma unroll
  for (int off=16; off<=32; off<<=1){
    mx = fmaxf(mx, __shfl_xor(mx, off));
    mn = fminf(mn, __shfl_xor(mn, off));
    sm += __shfl_xor(sm, off);
    sq += __shfl_xor(sq, off);
  }
  if (quad == 0){
    size_t ii = ((size_t)b*1024 + o0 + w*16 + m)*8 + nbk;
    pmax[ii] = mx; pmin[ii] = mn; psum[ii] = sm; psq[ii] = sq;
  }
}

__global__ __launch_bounds__(256) void k_stats5(const float* __restrict__ psum, const float* __restrict__ psq,
    const float* __restrict__ g5, const float* __restrict__ b5,
    float* __restrict__ sc5, float* __restrict__ sh5){
  int o = blockIdx.x*256 + threadIdx.x;
  float s=0.f, s2=0.f;
  for (int b=0;b<BB;b++){
    const float* ps = &psum[((size_t)b*1024 + o)*8];
    const float* pq = &psq [((size_t)b*1024 + o)*8];
    #pragma unroll
    for (int u=0;u<8;u++){ s += ps[u]; s2 += pq[u]; }
  }
  float cnt = (float)(BB*NN);
  float mean = s/cnt;
  float var = s2/cnt - mean*mean;
  float sc = g5[o] / sqrtf(var + LEPS);
  sc5[o] = sc;
  sh5[o] = b5[o] - mean*sc;
}

__global__ __launch_bounds__(256) void k_apply5(const float* __restrict__ pmax, const float* __restrict__ pmin,
    const float* __restrict__ sc5, const float* __restrict__ sh5, float* __restrict__ out){
  int i = blockIdx.x*256 + threadIdx.x;
  int o = i & 1023;
  float sc = sc5[o];
  float v;
  if (sc >= 0.f){
    const float* p = &pmax[(size_t)i*8];
    v = p[0];
    #pragma unroll
    for (int u=1;u<8;u++) v = fmaxf(v, p[u]);
  } else {
    const float* p = &pmin[(size_t)i*8];
    v = p[0];
    #pragma unroll
    for (int u=1;u<8;u++) v = fminf(v, p[u]);
  }
  out[i] = lrelu(v*sc + sh5[o]);
}

extern "C" void kernel_launch(void* const* d_in, const int* in_sizes, int n_in,
                              void* d_out, int out_size, void* d_ws, size_t ws_size,
                              hipStream_t stream){
  const float* x  = (const float*)d_in[0];
  const float* w1 = (const float*)d_in[1];
  const float* g1 = (const float*)d_in[2];
  const float* b1 = (const float*)d_in[3];
  const float* w2 = (const float*)d_in[4];
  const float* g2 = (const float*)d_in[5];
  const float* b2 = (const float*)d_in[6];
  const float* w3 = (const float*)d_in[7];
  const float* g3 = (const float*)d_in[8];
  const float* b3 = (const float*)d_in[9];
  const float* w4 = (const float*)d_in[10];
  const float* g4 = (const float*)d_in[11];
  const float* b4 = (const float*)d_in[12];
  const float* w5 = (const float*)d_in[13];
  const float* g5 = (const float*)d_in[14];
  const float* b5 = (const float*)d_in[15];
  float* out = (float*)d_out;
  float* ws = (float*)d_ws;

  const size_t F_PD   = 0;
  const size_t F_XT0  = F_PD   + (size_t)BB*NN*NN;
  const size_t F_XC   = F_XT0  + (size_t)BB*NN*4;
  const size_t F_CHS  = F_XC   + (size_t)BB*NN*XCCH;
  const size_t F_CHQ  = F_CHS  + (size_t)NSLOT*256;
  const size_t F_SCL  = F_CHQ  + (size_t)NSLOT*256;
  const size_t F_SHF  = F_SCL  + 256;
  const size_t F_SQ   = F_SHF  + 256;
  const size_t F_IDX  = F_SQ   + (size_t)BB*NN;
  const size_t F_PMAX = F_IDX  + (size_t)BB*NN*KK;
  const size_t F_PMIN = F_PMAX + (size_t)BB*1024*8;
  const size_t F_PSUM = F_PMIN + (size_t)BB*1024*8;
  const size_t F_PSQ  = F_PSUM + (size_t)BB*1024*8;
  const size_t F_SC5  = F_PSQ  + (size_t)BB*1024*8;
  const size_t F_SH5  = F_SC5  + 1024;
  const size_t F_XCB  = F_SH5  + 1024;
  const size_t F_WB   = F_XCB  + (size_t)BB*NN*XCCH/2;

  float* pd    = ws + F_PD;
  float* ctrb  = pd;                          // [B*N,256] fp32, alias pd (pd dead after k_topk)
  float* ymax  = pd + (size_t)16*1024*1024;
  float* ymin  = pd + (size_t)21*1024*1024;
  float* xt0   = ws + F_XT0;
  float* xc    = ws + F_XC;
  float* chsum = ws + F_CHS;
  float* chsq  = ws + F_CHQ;
  float* scl   = ws + F_SCL;
  float* shf   = ws + F_SHF;
  float* sqb   = ws + F_SQ;
  int*   idxb  = (int*)(ws + F_IDX);
  float* pmax  = ws + F_PMAX;
  float* pmin  = ws + F_PMIN;
  float* psum  = ws + F_PSUM;
  float* psq   = ws + F_PSQ;
  float* sc5   = ws + F_SC5;
  float* sh5   = ws + F_SH5;
  __hip_bfloat16* xcb = (__hip_bfloat16*)(ws + F_XCB);
  __hip_bfloat16* wb  = (__hip_bfloat16*)(ws + F_WB);
  __hip_bfloat16* w4d = wb;            // 256x128 (diff half of w4)
  __hip_bfloat16* w5b = wb + 32768;    // 1024x512

  (void)in_sizes; (void)n_in; (void)out_size; (void)ws_size;

  k_transpose<<<64, 256, 0, stream>>>(x, xt0);
  k_cvtw<<<(32768+255)/256,  256, 0, stream>>>(w4, w4d, 256, 128, 128, 128, 32768);
  k_cvtw<<<(524288+255)/256, 256, 0, stream>>>(w5, w5b, 512, 0, 512, 512, 524288);

  struct LayerP { const float* P; int stride; int Ci; int CiD; const float* W; const float* g; const float* b; int Oi; int off; };
  LayerP L[4] = {
    { xt0,    4,   3,   4,   w1, g1, b1,  64, 0   },
    { xc,     512, 64,  64,  w2, g2, b2,  64, 64  },
    { xc+64,  512, 64,  64,  w3, g3, b3, 128, 128 },
    { xc+128, 512, 128, 128, w4, g4, b4, 256, 256 },
  };

  for (int l=0; l<4; ++l){
    k_sq<<<64, 256, 0, stream>>>(L[l].P, L[l].stride, L[l].CiD, sqb);
    k_dist<<<dim3(16,16,8), 256, 0, stream>>>(L[l].P, L[l].stride, L[l].CiD, sqb, pd);
    k_topk<<<BB*NN/4, 256, 0, stream>>>(pd, idxb);
    hipMemsetAsync(chsum, 0, (size_t)NSLOT*256*2*sizeof(float), stream);
    k_ctr<<<dim3(BB*NN/64, L[l].Oi/64), 256, 0, stream>>>(L[l].P, L[l].stride, L[l].Ci, L[l].W, 2*L[l].Ci, ctrb);
    if (l < 3){
      k_conv<<<dim3(BB*NN/4, L[l].Oi/64), 256, 0, stream>>>(L[l].P, L[l].stride, L[l].Ci, L[l].W, L[l].Oi,
                                                            idxb, ctrb, ymax, ymin, chsum, chsq);
    } else {
      k_convm<<<dim3(BB*NN/16, 4), 256, 0, stream>>>(xcb+128, XCCH, w4d, 4,
                                                     idxb, ctrb, ymax, ymin, chsum, chsq);
    }
    k_bnstats<<<1, 256, 0, stream>>>(chsum, chsq, L[l].g, L[l].b, scl, shf, L[l].Oi);
    k_apply<<<(BB*NN*L[l].Oi + 255)/256, 256, 0, stream>>>(ymax, ymin, scl, shf, xc, xcb, L[l].off, L[l].Oi);
  }

  k_conv5m<<<dim3(8, 16, BB), 256, 0, stream>>>(xcb, w5b, pmax, pmin, psum, psq);
  k_stats5<<<4, 256, 0, stream>>>(psum, psq, g5, b5, sc5, sh5);
  k_apply5<<<(BB*1024)/256, 256, 0, stream>>>(pmax, pmin, sc5, sh5, out);
}

// Round 7
// 1301.002 us; speedup vs baseline: 2.5550x; 1.2137x over previous
//
#include <hip/hip_runtime.h>
#include <hip/hip_bf16.h>
#include <math.h>

#define BB 8
#define NN 2048
#define KK 20
#define XCCH 512
#define NSLOT 64
#define LEPS 1e-5f

typedef __attribute__((ext_vector_type(8))) short s8v;
typedef __attribute__((ext_vector_type(8))) _Float16 h8v;
typedef __attribute__((ext_vector_type(4))) float f32x4;

__device__ __forceinline__ float lrelu(float x){ return x >= 0.f ? x : 0.2f*x; }

__device__ __forceinline__ s8v bsub8(s8v a, s8v b){
  union U { s8v s; __hip_bfloat162 h[4]; } A, B, R;
  A.s = a; B.s = b;
  #pragma unroll
  for (int i=0;i<4;i++) R.h[i] = __hsub2(A.h[i], B.h[i]);
  return R.s;
}

// ---------- transpose x (B,3,N) -> xt0 (B*N,4) fp32 ----------
__global__ __launch_bounds__(256) void k_transpose(const float* __restrict__ x, float* __restrict__ xt){
  int i = blockIdx.x*256 + threadIdx.x;
  if (i >= BB*NN) return;
  int b = i >> 11, n = i & (NN-1);
  float4 v;
  v.x = x[(b*3+0)*NN + n];
  v.y = x[(b*3+1)*NN + n];
  v.z = x[(b*3+2)*NN + n];
  v.w = 0.f;
  reinterpret_cast<float4*>(xt)[i] = v;
}

// ---------- weight fp32 -> bf16 slice with K padding ----------
__global__ __launch_bounds__(256) void k_cvtw(const float* __restrict__ W, __hip_bfloat16* __restrict__ Wb,
                                              int Cs, int coff, int Ccnt, int Cpad, int total){
  int i = blockIdx.x*256 + threadIdx.x;
  if (i >= total) return;
  int o = i / Cpad, c = i - o*Cpad;
  Wb[i] = (c < Ccnt) ? __float2bfloat16(W[(size_t)o*Cs + coff + c]) : __float2bfloat16(0.f);
}

// ---------- split P fp32 -> hi/lo f16 (Cpad cols, zero-padded) ----------
__global__ __launch_bounds__(256) void k_split(const float* __restrict__ P, int stride, int Ci, int Cpad,
    _Float16* __restrict__ Ph, _Float16* __restrict__ Pl){
  int i = blockIdx.x*256 + threadIdx.x;
  if (i >= BB*NN*Cpad) return;
  int p = i / Cpad, c = i - p*Cpad;
  float v = (c < Ci) ? P[(size_t)p*stride + c] : 0.f;
  _Float16 h = (_Float16)v;
  float r = v - (float)h;
  Ph[i] = h;
  Pl[i] = (_Float16)r;
}

// ---------- squared norms from the split representation (consistent with k_distm) ----------
__global__ __launch_bounds__(256) void k_sqs(const _Float16* __restrict__ Ph,
    const _Float16* __restrict__ Pl, int Cpad, float* __restrict__ sq){
  int i = blockIdx.x*256 + threadIdx.x;
  if (i >= BB*NN) return;
  const _Float16* ph = Ph + (size_t)i*Cpad;
  const _Float16* pl = Pl + (size_t)i*Cpad;
  float s = 0.f;
  for (int c = 0; c < Cpad; ++c){
    float v = (float)ph[c] + (float)pl[c];
    s += v*v;
  }
  sq[i] = s;
}

// ---------- MFMA pairwise score: pd = 2*dot - sq_n - sq_m; dot via f16 split (4 MFMA, exact) ----------
// 128x128 tile, 4 waves; wave w -> rows [w*32, w*32+32), all 8 col-strips.
__global__ __launch_bounds__(256) void k_distm(
    const _Float16* __restrict__ Ph, const _Float16* __restrict__ Pl,
    int Cpad, int nchunk, const float* __restrict__ sq, float* __restrict__ pd)
{
  __shared__ _Float16 Ah[128*40];
  __shared__ _Float16 Al[128*40];
  __shared__ _Float16 Bh[128*40];
  __shared__ _Float16 Bl[128*40];
  int t = threadIdx.x;
  int w = t >> 6, lane = t & 63, m = lane & 15, quad = lane >> 4;
  int b = blockIdx.z;
  int n0 = blockIdx.y * 128, m0 = blockIdx.x * 128;
  const _Float16* PhB = Ph + (size_t)b*NN*Cpad;
  const _Float16* PlB = Pl + (size_t)b*NN*Cpad;
  f32x4 acc[2][8];
  #pragma unroll
  for (int s=0;s<2;s++)
    #pragma unroll
    for (int j=0;j<8;j++){ f32x4 z = {0.f,0.f,0.f,0.f}; acc[s][j] = z; }
  int r = t >> 1;
  int sg0 = t & 1;
  for (int ch=0; ch<nchunk; ++ch){
    int c0 = ch*32;
    #pragma unroll
    for (int k=0;k<2;k++){
      int seg = sg0 + 2*k;
      int go = c0 + seg*8;
      size_t an = (size_t)(n0+r)*Cpad + go;
      size_t bm = (size_t)(m0+r)*Cpad + go;
      *(h8v*)&Ah[r*40 + seg*8] = *(const h8v*)&PhB[an];
      *(h8v*)&Al[r*40 + seg*8] = *(const h8v*)&PlB[an];
      *(h8v*)&Bh[r*40 + seg*8] = *(const h8v*)&PhB[bm];
      *(h8v*)&Bl[r*40 + seg*8] = *(const h8v*)&PlB[bm];
    }
    __syncthreads();
    h8v ah0 = *(const h8v*)&Ah[(w*32 + m)*40 + quad*8];
    h8v al0 = *(const h8v*)&Al[(w*32 + m)*40 + quad*8];
    h8v ah1 = *(const h8v*)&Ah[(w*32 + 16 + m)*40 + quad*8];
    h8v al1 = *(const h8v*)&Al[(w*32 + 16 + m)*40 + quad*8];
    #pragma unroll
    for (int j=0;j<8;j++){
      h8v bh = *(const h8v*)&Bh[(j*16 + m)*40 + quad*8];
      h8v bl = *(const h8v*)&Bl[(j*16 + m)*40 + quad*8];
      acc[0][j] = __builtin_amdgcn_mfma_f32_16x16x32_f16(ah0, bh, acc[0][j], 0, 0, 0);
      acc[0][j] = __builtin_amdgcn_mfma_f32_16x16x32_f16(ah0, bl, acc[0][j], 0, 0, 0);
      acc[0][j] = __builtin_amdgcn_mfma_f32_16x16x32_f16(al0, bh, acc[0][j], 0, 0, 0);
      acc[0][j] = __builtin_amdgcn_mfma_f32_16x16x32_f16(al0, bl, acc[0][j], 0, 0, 0);
      acc[1][j] = __builtin_amdgcn_mfma_f32_16x16x32_f16(ah1, bh, acc[1][j], 0, 0, 0);
      acc[1][j] = __builtin_amdgcn_mfma_f32_16x16x32_f16(ah1, bl, acc[1][j], 0, 0, 0);
      acc[1][j] = __builtin_amdgcn_mfma_f32_16x16x32_f16(al1, bh, acc[1][j], 0, 0, 0);
      acc[1][j] = __builtin_amdgcn_mfma_f32_16x16x32_f16(al1, bl, acc[1][j], 0, 0, 0);
    }
    __syncthreads();
  }
  float sqm_[8];
  #pragma unroll
  for (int j=0;j<8;j++) sqm_[j] = sq[b*NN + m0 + j*16 + m];
  #pragma unroll
  for (int s=0;s<2;s++){
    int rbase = w*32 + s*16 + quad*4;
    #pragma unroll
    for (int rg=0; rg<4; rg++){
      float sqn = sq[b*NN + n0 + rbase + rg];
      size_t rowoff = ((size_t)b*NN + n0 + rbase + rg)*NN + m0 + m;
      #pragma unroll
      for (int j=0;j<8;j++){
        pd[rowoff + j*16] = 2.f*acc[s][j][rg] - sqn - sqm_[j];
      }
    }
  }
}

// ---------- top-20 per row: one wave per row, no barriers ----------
__global__ __launch_bounds__(256) void k_topk(const float* __restrict__ pd, int* __restrict__ idxo){
  int t = threadIdx.x;
  int l = t & 63;
  int row = blockIdx.x*4 + (t >> 6);
  const float4* rp = (const float4*)(pd + (size_t)row*NN);
  float r[32];
  #pragma unroll
  for (int j=0;j<8;j++){
    float4 v = rp[j*64 + l];
    r[j*4+0]=v.x; r[j*4+1]=v.y; r[j*4+2]=v.z; r[j*4+3]=v.w;
  }
  float bv = r[0]; int bi = 0;
  #pragma unroll
  for (int u=1;u<32;u++){ if (r[u] > bv){ bv = r[u]; bi = u; } }
  int myout = 0;
  for (int it=0; it<KK; ++it){
    int gidx = ((bi >> 2) << 8) | (l << 2) | (bi & 3);
    float v = bv; int gi = gidx;
    #pragma unroll
    for (int off=1; off<64; off<<=1){
      float ov = __shfl_xor(v, off);
      int og = __shfl_xor(gi, off);
      if (ov > v || (ov == v && og < gi)){ v = ov; gi = og; }
    }
    if (l == it) myout = gi;
    if (gi == gidx){
      r[bi] = -3.4e38f;
      bv = r[0]; bi = 0;
      #pragma unroll
      for (int u=1;u<32;u++){ if (r[u] > bv){ bv = r[u]; bi = u; } }
    }
  }
  if (l < KK) idxo[row*KK + l] = myout;
}

// ---------- ctr part: register-tiled GEMM, 64 pts x 64 outs per block ----------
__global__ __launch_bounds__(256) void k_ctr(const float* __restrict__ P, int stride, int Ci,
    const float* __restrict__ W, int twoCi, float* __restrict__ ctrb){
  __shared__ float Pt[64*17];
  __shared__ float Wt[64*17];
  int t = threadIdx.x, ty = t >> 4, tx = t & 15;
  int p0 = blockIdx.x*64, o0 = blockIdx.y*64;
  float acc[4][4];
  #pragma unroll
  for (int i=0;i<4;i++)
    #pragma unroll
    for (int j=0;j<4;j++) acc[i][j]=0.f;
  for (int c0 = 0; c0 < Ci; c0 += 16){
    #pragma unroll
    for (int q=0;q<4;q++){
      int e = t + 256*q;
      int r = e >> 4, cc = e & 15;
      int c = c0 + cc;
      bool ok = (c < Ci);
      Pt[r*17+cc] = ok ? P[(size_t)(p0+r)*stride + c] : 0.f;
      Wt[r*17+cc] = ok ? W[(size_t)(o0+r)*twoCi + c] : 0.f;
    }
    __syncthreads();
    #pragma unroll
    for (int j=0;j<16;j++){
      float a[4], bv[4];
      #pragma unroll
      for (int i=0;i<4;i++) a[i]  = Pt[(ty*4+i)*17 + j];
      #pragma unroll
      for (int i=0;i<4;i++) bv[i] = Wt[(tx*4+i)*17 + j];
      #pragma unroll
      for (int i=0;i<4;i++)
        #pragma unroll
        for (int jj=0;jj<4;jj++) acc[i][jj] += a[i]*bv[jj];
    }
    __syncthreads();
  }
  #pragma unroll
  for (int i=0;i<4;i++){
    *(float4*)&ctrb[(size_t)(p0+ty*4+i)*256 + o0 + tx*4] =
      make_float4(acc[i][0], acc[i][1], acc[i][2], acc[i][3]);
  }
}

// ---------- fp32 diff-conv (layers 1-3): K = Ci only; epilogue adds ctr part ----------
__global__ __launch_bounds__(256) void k_conv(const float* __restrict__ P, int stride, int Ci,
    const float* __restrict__ W, int Oi, const int* __restrict__ idxg,
    const float* __restrict__ ctrb,
    float* __restrict__ ymax, float* __restrict__ ymin,
    float* __restrict__ chsum, float* __restrict__ chsq){
  __shared__ int lidx[80];
  __shared__ float ft[80*17];
  __shared__ float wt[16*68];
  __shared__ float red[16*16*4*4];
  int t = threadIdx.x;
  int blk = blockIdx.x;
  int b = blk / (NN/4);
  int n0 = (blk % (NN/4))*4;
  int o0 = blockIdx.y*64;
  if (t < 80) lidx[t] = idxg[((size_t)b*NN + n0 + t/20)*KK + (t%20)];
  int tr = t >> 4, tc = t & 15;
  int twoCi = 2*Ci;
  const float* Pb = P + (size_t)b*NN*stride;
  float acc[5][4];
  #pragma unroll
  for (int i=0;i<5;i++){ acc[i][0]=0.f; acc[i][1]=0.f; acc[i][2]=0.f; acc[i][3]=0.f; }
  int nchunks = (Ci + 15)/16;
  __syncthreads();
  for (int ch=0; ch<nchunks; ++ch){
    int c0 = ch*16;
    #pragma unroll
    for (int q=0;q<5;q++){
      int e = t + 256*q;
      int r = e >> 4, cc = e & 15;
      int c = c0 + cc;
      int n = n0 + r/20;
      float v = 0.f;
      if (c < Ci){
        int nbn = lidx[r];
        v = Pb[(size_t)nbn*stride + c] - Pb[(size_t)n*stride + c];
      }
      ft[r*17+cc] = v;
    }
    #pragma unroll
    for (int q=0;q<4;q++){
      int e = t + 256*q;
      int oi = e >> 4, cc = e & 15;
      int c = c0 + cc;
      wt[cc*68 + oi] = (c < Ci) ? W[(size_t)(o0+oi)*twoCi + Ci + c] : 0.f;
    }
    __syncthreads();
    #pragma unroll
    for (int j=0;j<16;j++){
      float4 wv = *reinterpret_cast<const float4*>(&wt[j*68 + tc*4]);
      #pragma unroll
      for (int i=0;i<5;i++){
        float a = ft[(tr*5+i)*17 + j];
        acc[i][0] += a*wv.x;
        acc[i][1] += a*wv.y;
        acc[i][2] += a*wv.z;
        acc[i][3] += a*wv.w;
      }
    }
    __syncthreads();
  }
  int nloc = tr >> 2;
  const float4 cv4 = *(const float4*)&ctrb[((size_t)b*NN + n0 + nloc)*256 + o0 + tc*4];
  const float* cvp = (const float*)&cv4;
  #pragma unroll
  for (int jj=0;jj<4;jj++){
    float cc = cvp[jj];
    float y0 = acc[0][jj] + cc;
    float mx = y0, mn = y0, s = y0, s2 = y0*y0;
    #pragma unroll
    for (int i=1;i<5;i++){
      float y = acc[i][jj] + cc;
      mx = fmaxf(mx,y); mn = fminf(mn,y); s += y; s2 += y*y;
    }
    float* rr = &red[((t*4)+jj)*4];
    rr[0]=mx; rr[1]=mn; rr[2]=s; rr[3]=s2;
  }
  __syncthreads();
  float ssave[4], s2save[4];
  bool isS2 = ((tr & 3) == 0);
  if (isS2){
    int n = n0 + (tr >> 2);
    float omax[4], omin[4];
    #pragma unroll
    for (int jj=0;jj<4;jj++){
      float mx=-3.4e38f, mn=3.4e38f, s=0.f, s2=0.f;
      #pragma unroll
      for (int u=0;u<4;u++){
        const float* rr = &red[((((tr+u)*16+tc)*4)+jj)*4];
        mx = fmaxf(mx, rr[0]); mn = fminf(mn, rr[1]); s += rr[2]; s2 += rr[3];
      }
      omax[jj]=mx; omin[jj]=mn; ssave[jj]=s; s2save[jj]=s2;
    }
    size_t base = ((size_t)b*NN + n)*256 + o0 + tc*4;
    *reinterpret_cast<float4*>(&ymax[base]) = make_float4(omax[0],omax[1],omax[2],omax[3]);
    *reinterpret_cast<float4*>(&ymin[base]) = make_float4(omin[0],omin[1],omin[2],omin[3]);
  }
  __syncthreads();
  if (isS2){
    float* rr  = &red[(((tr*16+tc)*4)+0)*4];
    rr[0]=ssave[0]; rr[1]=ssave[1]; rr[2]=ssave[2]; rr[3]=ssave[3];
    float* rr2 = &red[(((tr*16+tc)*4)+1)*4];
    rr2[0]=s2save[0]; rr2[1]=s2save[1]; rr2[2]=s2save[2]; rr2[3]=s2save[3];
  }
  __syncthreads();
  if (tr == 0){
    int slot = blk & (NSLOT-1);
    #pragma unroll
    for (int jj=0;jj<4;jj++){
      float s = 0.f, s2 = 0.f;
      #pragma unroll
      for (int u=0;u<16;u+=4){
        s  += red[(((u*16+tc)*4)+0)*4 + jj];
        s2 += red[(((u*16+tc)*4)+1)*4 + jj];
      }
      int o = o0 + tc*4 + jj;
      atomicAdd(&chsum[slot*256 + o], s);
      atomicAdd(&chsq[slot*256 + o], s2);
    }
  }
}

// ---------- MFMA diff-conv (layer 4): K = 128; epilogue adds fp32 ctr part ----------
__global__ __launch_bounds__(256) void k_convm(
    const __hip_bfloat16* __restrict__ PB, int stride,
    const __hip_bfloat16* __restrict__ Wd, int nchunk,
    const int* __restrict__ idxg, const float* __restrict__ ctrb,
    float* __restrict__ ymax, float* __restrict__ ymin,
    float* __restrict__ chsum, float* __restrict__ chsq)
{
  __shared__ __align__(16) char smem[40960];
  __hip_bfloat16* As = (__hip_bfloat16*)smem;
  float* redmx = (float*)smem;
  float* redmn = (float*)(smem + 20480);
  __shared__ int lidx[320];
  int t = threadIdx.x;
  int w = t >> 6, lane = t & 63, m = lane & 15, quad = lane >> 4;
  int p0 = blockIdx.x * 16;
  int b  = p0 >> 11;
  int o0 = blockIdx.y * 64;
  int Kpad = nchunk * 32;
  for (int q = t; q < 320; q += 256) lidx[q] = idxg[p0*KK + q];
  f32x4 acc[20];
  #pragma unroll
  for (int s=0;s<20;s++){ f32x4 z = {0.f,0.f,0.f,0.f}; acc[s] = z; }
  __syncthreads();

  const __hip_bfloat16* wrow = Wd + (size_t)(o0 + w*16 + m)*Kpad + quad*8;

  unsigned offn[5], offnb[5]; int lo[5];
  #pragma unroll
  for (int q=0;q<5;q++){
    int s = t + 256*q;
    int rr = s >> 2, seg = s & 3;
    int pp = (rr*6554) >> 17;
    int n_g  = p0 + pp;
    int nb_g = (b<<11) + lidx[rr];
    offn[q]  = (unsigned)n_g*stride  + seg*8;
    offnb[q] = (unsigned)nb_g*stride + seg*8;
    lo[q] = rr*40 + seg*8;
  }
  for (int ch=0; ch<nchunk; ++ch){
    int c0 = ch*32;
    #pragma unroll
    for (int q=0;q<5;q++){
      s8v a  = *(const s8v*)&PB[offnb[q] + c0];
      s8v bb = *(const s8v*)&PB[offn[q]  + c0];
      *(s8v*)&As[lo[q]] = bsub8(a, bb);
    }
    __syncthreads();
    s8v bf = *(const s8v*)(wrow + c0);
    #pragma unroll
    for (int s=0;s<20;s++){
      s8v af = *(const s8v*)&As[(s*16+m)*40 + quad*8];
      acc[s] = __builtin_amdgcn_mfma_f32_16x16x32_bf16(af, bf, acc[s], 0, 0, 0);
    }
    __syncthreads();
  }

  int col = o0 + w*16 + m;
  float sm = 0.f, sq = 0.f;
  #pragma unroll
  for (int s=0;s<20;s++){
    int row0 = s*16 + quad*4;
    int pp = (row0*6554) >> 17;
    float cc = ctrb[(size_t)(p0+pp)*256 + col];
    f32x4 a = acc[s];
    a.x += cc; a.y += cc; a.z += cc; a.w += cc;
    float mx = fmaxf(fmaxf(a.x,a.y), fmaxf(a.z,a.w));
    float mn = fminf(fminf(a.x,a.y), fminf(a.z,a.w));
    sm += a.x + a.y + a.z + a.w;
    sq += a.x*a.x + a.y*a.y + a.z*a.z + a.w*a.w;
    int gq = s*4 + quad;
    redmx[gq*64 + w*16 + m] = mx;
    redmn[gq*64 + w*16 + m] = mn;
  }
  sm += __shfl_xor(sm, 16); sq += __shfl_xor(sq, 16);
  sm += __shfl_xor(sm, 32); sq += __shfl_xor(sq, 32);
  if (quad == 0){
    int slot = blockIdx.x & (NSLOT-1);
    atomicAdd(&chsum[slot*256 + col], sm);
    atomicAdd(&chsq [slot*256 + col], sq);
  }
  __syncthreads();
  #pragma unroll
  for (int q=0;q<4;q++){
    int i = t + 256*q;
    int pp = i >> 6, c2 = i & 63;
    float mx = redmx[(pp*5)*64 + c2];
    float mn = redmn[(pp*5)*64 + c2];
    #pragma unroll
    for (int u=1;u<5;u++){
      mx = fmaxf(mx, redmx[(pp*5+u)*64 + c2]);
      mn = fminf(mn, redmn[(pp*5+u)*64 + c2]);
    }
    size_t base = ((size_t)(p0+pp))*256 + o0 + c2;
    ymax[base] = mx;
    ymin[base] = mn;
  }
}

// ---------- BN stats finalize ----------
__global__ __launch_bounds__(256) void k_bnstats(const float* __restrict__ chsum, const float* __restrict__ chsq,
    const float* __restrict__ g, const float* __restrict__ bet,
    float* __restrict__ scl, float* __restrict__ shf, int Oi){
  int o = threadIdx.x;
  if (o >= Oi) return;
  float s=0.f, s2=0.f;
  for (int u=0;u<NSLOT;u++){ s += chsum[u*256+o]; s2 += chsq[u*256+o]; }
  float cnt = (float)(BB*NN*KK);
  float mean = s/cnt;
  float var = s2/cnt - mean*mean;
  float sc = g[o] / sqrtf(var + LEPS);
  scl[o] = sc;
  shf[o] = bet[o] - mean*sc;
}

// ---------- apply BN+LReLU, write fp32 xc + bf16 xcb ----------
__global__ __launch_bounds__(256) void k_apply(const float* __restrict__ ymax, const float* __restrict__ ymin,
    const float* __restrict__ scl, const float* __restrict__ shf,
    float* __restrict__ xc, __hip_bfloat16* __restrict__ xcb, int off, int Oi){
  int i = blockIdx.x*256 + threadIdx.x;
  if (i >= BB*NN*Oi) return;
  int o = i & (Oi-1);
  size_t p = (size_t)((unsigned)i / (unsigned)Oi);
  float sc = scl[o];
  float v = (sc >= 0.f) ? ymax[p*256+o] : ymin[p*256+o];
  float r = lrelu(v*sc + shf[o]);
  xc [p*XCCH + off + o] = r;
  xcb[p*XCCH + off + o] = __float2bfloat16(r);
}

// ---------- MFMA conv5 ----------
__global__ __launch_bounds__(256) void k_conv5m(const __hip_bfloat16* __restrict__ xcb,
    const __hip_bfloat16* __restrict__ w5b,
    float* __restrict__ pmax, float* __restrict__ pmin,
    float* __restrict__ psum, float* __restrict__ psq)
{
  int t = threadIdx.x, w = t >> 6, lane = t & 63, m = lane & 15, quad = lane >> 4;
  int nbk = blockIdx.x, b = blockIdx.z;
  int o0 = blockIdx.y * 64;
  int n0 = nbk * 256;
  const __hip_bfloat16* arow = xcb + (size_t)(b*NN + n0 + m)*XCCH + quad*8;
  const __hip_bfloat16* brow = w5b + (size_t)(o0 + w*16 + m)*XCCH + quad*8;
  f32x4 acc[16];
  #pragma unroll
  for (int s=0;s<16;s++){ f32x4 z = {0.f,0.f,0.f,0.f}; acc[s] = z; }
  for (int ch=0; ch<16; ++ch){
    int c0 = ch*32;
    s8v bf = *(const s8v*)(brow + c0);
    #pragma unroll
    for (int s=0;s<16;s++){
      s8v af = *(const s8v*)(arow + (size_t)s*16*XCCH + c0);
      acc[s] = __builtin_amdgcn_mfma_f32_16x16x32_bf16(af, bf, acc[s], 0, 0, 0);
    }
  }
  float mx = -3.4e38f, mn = 3.4e38f, sm = 0.f, sq = 0.f;
  #pragma unroll
  for (int s=0;s<16;s++){
    f32x4 a = acc[s];
    mx = fmaxf(mx, fmaxf(fmaxf(a.x,a.y), fmaxf(a.z,a.w)));
    mn = fminf(mn, fminf(fminf(a.x,a.y), fminf(a.z,a.w)));
    sm += a.x + a.y + a.z + a.w;
    sq += a.x*a.x + a.y*a.y + a.z*a.z + a.w*a.w;
  }
  #pragma unroll
  for (int off=16; off<=32; off<<=1){
    mx = fmaxf(mx, __shfl_xor(mx, off));
    mn = fminf(mn, __shfl_xor(mn, off));
    sm += __shfl_xor(sm, off);
    sq += __shfl_xor(sq, off);
  }
  if (quad == 0){
    size_t ii = ((size_t)b*1024 + o0 + w*16 + m)*8 + nbk;
    pmax[ii] = mx; pmin[ii] = mn; psum[ii] = sm; psq[ii] = sq;
  }
}

__global__ __launch_bounds__(256) void k_stats5(const float* __restrict__ psum, const float* __restrict__ psq,
    const float* __restrict__ g5, const float* __restrict__ b5,
    float* __restrict__ sc5, float* __restrict__ sh5){
  int o = blockIdx.x*256 + threadIdx.x;
  float s=0.f, s2=0.f;
  for (int b=0;b<BB;b++){
    const float* ps = &psum[((size_t)b*1024 + o)*8];
    const float* pq = &psq [((size_t)b*1024 + o)*8];
    #pragma unroll
    for (int u=0;u<8;u++){ s += ps[u]; s2 += pq[u]; }
  }
  float cnt = (float)(BB*NN);
  float mean = s/cnt;
  float var = s2/cnt - mean*mean;
  float sc = g5[o] / sqrtf(var + LEPS);
  sc5[o] = sc;
  sh5[o] = b5[o] - mean*sc;
}

__global__ __launch_bounds__(256) void k_apply5(const float* __restrict__ pmax, const float* __restrict__ pmin,
    const float* __restrict__ sc5, const float* __restrict__ sh5, float* __restrict__ out){
  int i = blockIdx.x*256 + threadIdx.x;
  int o = i & 1023;
  float sc = sc5[o];
  float v;
  if (sc >= 0.f){
    const float* p = &pmax[(size_t)i*8];
    v = p[0];
    #pragma unroll
    for (int u=1;u<8;u++) v = fmaxf(v, p[u]);
  } else {
    const float* p = &pmin[(size_t)i*8];
    v = p[0];
    #pragma unroll
    for (int u=1;u<8;u++) v = fminf(v, p[u]);
  }
  out[i] = lrelu(v*sc + sh5[o]);
}

extern "C" void kernel_launch(void* const* d_in, const int* in_sizes, int n_in,
                              void* d_out, int out_size, void* d_ws, size_t ws_size,
                              hipStream_t stream){
  const float* x  = (const float*)d_in[0];
  const float* w1 = (const float*)d_in[1];
  const float* g1 = (const float*)d_in[2];
  const float* b1 = (const float*)d_in[3];
  const float* w2 = (const float*)d_in[4];
  const float* g2 = (const float*)d_in[5];
  const float* b2 = (const float*)d_in[6];
  const float* w3 = (const float*)d_in[7];
  const float* g3 = (const float*)d_in[8];
  const float* b3 = (const float*)d_in[9];
  const float* w4 = (const float*)d_in[10];
  const float* g4 = (const float*)d_in[11];
  const float* b4 = (const float*)d_in[12];
  const float* w5 = (const float*)d_in[13];
  const float* g5 = (const float*)d_in[14];
  const float* b5 = (const float*)d_in[15];
  float* out = (float*)d_out;
  float* ws = (float*)d_ws;

  const size_t F_PD   = 0;
  const size_t F_XT0  = F_PD   + (size_t)BB*NN*NN;
  const size_t F_XC   = F_XT0  + (size_t)BB*NN*4;
  const size_t F_CHS  = F_XC   + (size_t)BB*NN*XCCH;
  const size_t F_CHQ  = F_CHS  + (size_t)NSLOT*256;
  const size_t F_SCL  = F_CHQ  + (size_t)NSLOT*256;
  const size_t F_SHF  = F_SCL  + 256;
  const size_t F_SQ   = F_SHF  + 256;
  const size_t F_IDX  = F_SQ   + (size_t)BB*NN;
  const size_t F_PMAX = F_IDX  + (size_t)BB*NN*KK;
  const size_t F_PMIN = F_PMAX + (size_t)BB*1024*8;
  const size_t F_PSUM = F_PMIN + (size_t)BB*1024*8;
  const size_t F_PSQ  = F_PSUM + (size_t)BB*1024*8;
  const size_t F_SC5  = F_PSQ  + (size_t)BB*1024*8;
  const size_t F_SH5  = F_SC5  + 1024;
  const size_t F_XCB  = F_SH5  + 1024;
  const size_t F_WB   = F_XCB  + (size_t)BB*NN*XCCH/2;      // wb region
  const size_t F_PH   = F_WB   + 278528;                    // Ph: BB*NN*128 f16 = 1048576 floats
  const size_t F_PL   = F_PH   + 1048576;

  float* pd    = ws + F_PD;
  float* ctrb  = pd;                          // alias pd (pd dead after k_topk)
  float* ymax  = pd + (size_t)16*1024*1024;
  float* ymin  = pd + (size_t)21*1024*1024;
  float* xt0   = ws + F_XT0;
  float* xc    = ws + F_XC;
  float* chsum = ws + F_CHS;
  float* chsq  = ws + F_CHQ;
  float* scl   = ws + F_SCL;
  float* shf   = ws + F_SHF;
  float* sqb   = ws + F_SQ;
  int*   idxb  = (int*)(ws + F_IDX);
  float* pmax  = ws + F_PMAX;
  float* pmin  = ws + F_PMIN;
  float* psum  = ws + F_PSUM;
  float* psq   = ws + F_PSQ;
  float* sc5   = ws + F_SC5;
  float* sh5   = ws + F_SH5;
  __hip_bfloat16* xcb = (__hip_bfloat16*)(ws + F_XCB);
  __hip_bfloat16* wb  = (__hip_bfloat16*)(ws + F_WB);
  __hip_bfloat16* w4d = wb;            // 256x128 (diff half of w4)
  __hip_bfloat16* w5b = wb + 32768;    // 1024x512
  _Float16* Ph  = (_Float16*)(ws + F_PH);
  _Float16* Pl  = (_Float16*)(ws + F_PL);

  (void)in_sizes; (void)n_in; (void)out_size; (void)ws_size;

  k_transpose<<<64, 256, 0, stream>>>(x, xt0);
  k_cvtw<<<(32768+255)/256,  256, 0, stream>>>(w4, w4d, 256, 128, 128, 128, 32768);
  k_cvtw<<<(524288+255)/256, 256, 0, stream>>>(w5, w5b, 512, 0, 512, 512, 524288);

  struct LayerP { const float* P; int stride; int Ci; int CiD; int Cpad;
                  const float* W; const float* g; const float* b; int Oi; int off; };
  LayerP L[4] = {
    { xt0,    4,   3,   4,   32,  w1, g1, b1,  64, 0   },
    { xc,     512, 64,  64,  64,  w2, g2, b2,  64, 64  },
    { xc+64,  512, 64,  64,  64,  w3, g3, b3, 128, 128 },
    { xc+128, 512, 128, 128, 128, w4, g4, b4, 256, 256 },
  };

  for (int l=0; l<4; ++l){
    int Cpad = L[l].Cpad, nchunk = Cpad/32;
    k_split<<<(BB*NN*Cpad+255)/256, 256, 0, stream>>>(L[l].P, L[l].stride, L[l].CiD, Cpad, Ph, Pl);
    k_sqs<<<64, 256, 0, stream>>>(Ph, Pl, Cpad, sqb);
    k_distm<<<dim3(16,16,8), 256, 0, stream>>>(Ph, Pl, Cpad, nchunk, sqb, pd);
    k_topk<<<BB*NN/4, 256, 0, stream>>>(pd, idxb);
    hipMemsetAsync(chsum, 0, (size_t)NSLOT*256*2*sizeof(float), stream);
    k_ctr<<<dim3(BB*NN/64, L[l].Oi/64), 256, 0, stream>>>(L[l].P, L[l].stride, L[l].Ci, L[l].W, 2*L[l].Ci, ctrb);
    if (l < 3){
      k_conv<<<dim3(BB*NN/4, L[l].Oi/64), 256, 0, stream>>>(L[l].P, L[l].stride, L[l].Ci, L[l].W, L[l].Oi,
                                                            idxb, ctrb, ymax, ymin, chsum, chsq);
    } else {
      k_convm<<<dim3(BB*NN/16, 4), 256, 0, stream>>>(xcb+128, XCCH, w4d, 4,
                                                     idxb, ctrb, ymax, ymin, chsum, chsq);
    }
    k_bnstats<<<1, 256, 0, stream>>>(chsum, chsq, L[l].g, L[l].b, scl, shf, L[l].Oi);
    k_apply<<<(BB*NN*L[l].Oi + 255)/256, 256, 0, stream>>>(ymax, ymin, scl, shf, xc, xcb, L[l].off, L[l].Oi);
  }

  k_conv5m<<<dim3(8, 16, BB), 256, 0, stream>>>(xcb, w5b, pmax, pmin, psum, psq);
  k_stats5<<<4, 256, 0, stream>>>(psum, psq, g5, b5, sc5, sh5);
  k_apply5<<<(BB*1024)/256, 256, 0, stream>>>(pmax, pmin, sc5, sh5, out);
}